// Round 6
// baseline (3192.193 us; speedup 1.0000x reference)
//
#include <hip/hip_runtime.h>
#include <math.h>

// ---------------------------------------------------------------------------
// MonLipLayer forward on MI355X.  R10 = R9 with compile fix (stray sBhDummy
// macro used before definition; replaced with direct dB).  R9: phase-4 NS
// chain (9 coupled iterations, was 18 serialized dispatches ~540us dominated
// by launch/drain overhead) fused into ONE persistent kernel `ns_fused` with
// a two-level device-scope grid barrier (768 blocks = 3/CU co-resident
// @32KB LDS; AGENT-scope atomics + __threadfence for cross-XCD visibility;
// monotone generation counter -- no read/arrive race).  Job map [Q,R,R]
// balances 2:1 Q/R work per CU.  Depth-2 prefetch restricted to PANEL<=8KB
// (R8's 48KB E_PRE occupancy regression reverted).  R7: counted-vmcnt
// multi-buffer pipeline (kept).
// Math unchanged.  C = alpha * A(MxK,row) * Bt(NxK,row)^T + beta * D.
// ---------------------------------------------------------------------------

using s8v = __attribute__((ext_vector_type(8))) short;   // 8 x bf16
using f4v = __attribute__((ext_vector_type(4))) float;
typedef unsigned short ush;
typedef unsigned int uint32;

#define DEV __device__ __forceinline__

DEV float b2f(ush u){ union{unsigned int i; float f;} v; v.i = ((unsigned int)u)<<16; return v.f; }
DEV ush f2b(float f){
  union{float f; unsigned int i;} v; v.f = f;
  unsigned int u = v.i;
  return (ush)((u + 0x7fffu + ((u>>16)&1u)) >> 16);
}

typedef __attribute__((address_space(1))) void gvoid;
typedef __attribute__((address_space(3))) void lvoid;
DEV void gload16(const void* g, void* l){
  __builtin_amdgcn_global_load_lds((gvoid*)g, (lvoid*)l, 16, 0, 0);
}

DEV void st16(ush* dst, const ush* a){
  *(int4*)dst = *(const int4*)a; *(int4*)(dst+8) = *(const int4*)(a+8);
}

struct GA {
  const ush *A0h, *A0l; long lda0;
  const ush *A1h, *A1l; long lda1; int ksplit;
  const ush *Bh, *Bl; long ldb;
  int K, M, N;
  float alpha, beta;
  long sA, sB, sO, sD;
  void *o0,*o1,*o2,*o3,*o4;
  const void *e0,*e1;
  long ldo0, ldo1, ldE;
};

enum { E_F32=0, E_BF16=1, E_BF16T2=2, E_SPLIT=3, E_QW=4, E_PRE=5, E_GH=6, E_OUT=7 };

template<int BM, int BN, int EPI, bool SPLIT, bool TRX>
__global__ __launch_bounds__(256) void gemm_k(GA gq, GA gr, int zsplit)
{
  // ---- shared memory: NBUF staging buffers, tb aliased on top ------------
  constexpr int AH = BM*32;                        // ush per A panel
  constexpr int BH = BN*32;                        // ush per B panel
  constexpr int PANEL = (AH+BH) * (SPLIT ? 2 : 1); // one buffer (ush)
  constexpr int DEPTH = (PANEL <= 4096) ? 2 : 1;   // prefetch depth
  constexpr int NBUF  = DEPTH + 2;
  constexpr int TBN = TRX ? 64*65*2 : 0;           // tb as ush count
  constexpr int SMN = (NBUF*PANEL > TBN) ? NBUF*PANEL : TBN;
  __shared__ ush smem[SMN] __attribute__((aligned(16)));
  uint32* tb = (uint32*)smem;                      // valid only after k-loop

  // loads issued per thread per STAGE (compile-time)
  constexpr int LPS = (BM/64 + BN/64) * (SPLIT ? 2 : 1);

  GA g; int bz;
  if ((int)blockIdx.z < zsplit){ g = gq; bz = blockIdx.z; }
  else                         { g = gr; bz = blockIdx.z - zsplit; }

  // supertile swizzle: groups of 8 block-rows, column-major inside a group
  const int gx = gridDim.x, gy = gridDim.y;
  const int lin = blockIdx.y*gx + blockIdx.x;
  const int per = gx*8;
  const int grp = lin / per;
  const int rem = lin - grp*per;
  int gh = gy - grp*8; if (gh > 8) gh = 8;
  const int by = grp*8 + rem % gh;
  const int bx = rem / gh;
  const int m0 = by * BM;
  const int n0 = bx * BN;
  if (m0 >= g.M || n0 >= g.N) return;

  const int t = threadIdx.x;
  const int lane = t & 63;
  const int wave = t >> 6;
  const int wm = (wave >> 1) * (BM/2);
  const int wn = (wave & 1) * (BN/2);
  constexpr int MT = BM/32;
  constexpr int NT = BN/32;

  const ush* Ah  = g.A0h + (long)bz*g.sA;
  const ush* Alp = SPLIT ? g.A0l + (long)bz*g.sA : nullptr;
  const ush* Bhp = g.Bh  + (long)bz*g.sB;
  const ush* Blp = SPLIT ? g.Bl  + (long)bz*g.sB : nullptr;

  f4v acc[MT][NT];
  #pragma unroll
  for (int i=0;i<MT;i++)
    #pragma unroll
    for (int j=0;j<NT;j++) acc[i][j] = f4v{0.f,0.f,0.f,0.f};

  const int sr  = lane >> 2;
  const int scg = lane & 3;

  // stage one 32-K tile into buffer nb (0..NBUF-1)
  auto STAGE = [&](int k0, int nb){
    ush* dA  = smem + nb*PANEL;
    ush* dB  = dA + AH;
    ush* dAl = dB + BH;
    ush* dBl = dAl + AH;
    #pragma unroll
    for (int p = 0; p < BM/64; ++p) {
      const int lr = wave*16 + sr + p*64;
      const int gc = scg ^ ((lr>>1)&3);
      const int kc = k0 + gc*8;
      long aoff; const ush* gp;
      if (kc < g.ksplit){ aoff = (long)(m0+lr)*g.lda0 + kc;               gp = Ah + aoff; }
      else              { aoff = (long)(m0+lr)*g.lda1 + (kc - g.ksplit);  gp = g.A1h + aoff; }
      gload16(gp, &dA[(wave*16 + p*64)*32]);
      if (SPLIT) gload16(Alp + aoff, &dAl[(wave*16 + p*64)*32]);
    }
    #pragma unroll
    for (int p = 0; p < BN/64; ++p) {
      const int lr = wave*16 + sr + p*64;
      const int gc = scg ^ ((lr>>1)&3);
      const long boff = (long)(n0+lr)*g.ldb + k0 + gc*8;
      gload16(Bhp + boff, &dB[(wave*16 + p*64)*32]);
      if (SPLIT) gload16(Blp + boff, &dBl[(wave*16 + p*64)*32]);
    }
  };

  // ---- K-loop: depth-DEPTH prefetch, counted vmcnt, ONE s_barrier/step ----
  STAGE(0, 0);
  if (DEPTH == 2 && g.K > 32) STAGE(32, 1);
  int cur = 0;
  for (int k0 = 0; k0 < g.K; k0 += 32) {
    const int rem_steps = ((g.K - k0) >> 5) - 1;   // steps after current
    if (DEPTH == 2) {
      if (rem_steps >= 2) {
        const int nb = (cur+2 >= NBUF) ? cur+2-NBUF : cur+2;
        STAGE(k0 + 64, nb);
        asm volatile("s_waitcnt vmcnt(%0)" :: "n"(2*LPS) : "memory");
      } else if (rem_steps == 1) {
        asm volatile("s_waitcnt vmcnt(%0)" :: "n"(LPS) : "memory");
      } else {
        asm volatile("s_waitcnt vmcnt(0)" ::: "memory");
      }
    } else {
      if (rem_steps >= 1) {
        const int nb = (cur+1 >= NBUF) ? cur+1-NBUF : cur+1;
        STAGE(k0 + 32, nb);
        asm volatile("s_waitcnt vmcnt(%0)" :: "n"(LPS) : "memory");
      } else {
        asm volatile("s_waitcnt vmcnt(0)" ::: "memory");
      }
    }
    __builtin_amdgcn_sched_barrier(0);
    __builtin_amdgcn_s_barrier();      // all waves have buf(cur) resident
    __builtin_amdgcn_sched_barrier(0);

    const ush* rA  = smem + cur*PANEL;
    const ush* rB  = rA + AH;
    const ush* rAl = rB + BH;
    const ush* rBl = rAl + AH;

    const int fr = lane & 15;
    const int cc = lane >> 4;
    s8v af[MT], bf_[NT];
    #pragma unroll
    for (int i=0;i<MT;i++){ const int row = wm + i*16 + fr;
      af[i] = *(const s8v*)(&rA[row*32 + ((cc ^ ((row>>1)&3))<<3)]); }
    #pragma unroll
    for (int j=0;j<NT;j++){ const int row = wn + j*16 + fr;
      bf_[j] = *(const s8v*)(&rB[row*32 + ((cc ^ ((row>>1)&3))<<3)]); }
    #pragma unroll
    for (int i=0;i<MT;i++)
      #pragma unroll
      for (int j=0;j<NT;j++)
        acc[i][j] = __builtin_amdgcn_mfma_f32_16x16x32_bf16(af[i], bf_[j], acc[i][j], 0,0,0);
    if (SPLIT) {
      s8v al2[MT], bl2[NT];
      #pragma unroll
      for (int j=0;j<NT;j++){ const int row = wn + j*16 + fr;
        bl2[j] = *(const s8v*)(&rBl[row*32 + ((cc ^ ((row>>1)&3))<<3)]); }
      #pragma unroll
      for (int i=0;i<MT;i++){ const int row = wm + i*16 + fr;
        al2[i] = *(const s8v*)(&rAl[row*32 + ((cc ^ ((row>>1)&3))<<3)]); }
      #pragma unroll
      for (int i=0;i<MT;i++)
        #pragma unroll
        for (int j=0;j<NT;j++)
          acc[i][j] = __builtin_amdgcn_mfma_f32_16x16x32_bf16(af[i], bl2[j], acc[i][j], 0,0,0);
      #pragma unroll
      for (int i=0;i<MT;i++)
        #pragma unroll
        for (int j=0;j<NT;j++)
          acc[i][j] = __builtin_amdgcn_mfma_f32_16x16x32_bf16(al2[i], bf_[j], acc[i][j], 0,0,0);
    }
    cur = (cur+1 >= NBUF) ? 0 : cur+1;
  }

  // before epilogue: TRX writes tb over the staging alias -> need all waves
  // past their final MFMA reads of smem.
  if constexpr (TRX) __syncthreads();

  // ---------------- epilogue: direct writes (+ LDS staging for TRX) --------
  #pragma unroll
  for (int i=0;i<MT;i++)
    #pragma unroll
    for (int j=0;j<NT;j++)
      #pragma unroll
      for (int r=0;r<4;r++) {
        const int lrow = wm + i*16 + ((lane>>4)<<2) + r;
        const int lcol = wn + j*16 + (lane & 15);
        const int grow = m0 + lrow;
        const int gcol = n0 + lcol;
        float v = g.alpha * acc[i][j][r];
        if constexpr (EPI == E_F32) {
          if (g.e0) v += g.beta * ((const float*)g.e0)[(long)bz*g.sD + (long)grow*g.ldo0 + gcol];
          ((float*)g.o0)[(long)bz*g.sO + (long)grow*g.ldo0 + gcol] = v;
        } else if constexpr (EPI == E_BF16) {
          if (g.e0) v += g.beta * b2f(((const ush*)g.e0)[(long)bz*g.sD + (long)grow*g.ldo0 + gcol]);
          ((ush*)g.o0)[(long)bz*g.sO + (long)grow*g.ldo0 + gcol] = f2b(v);
        } else if constexpr (EPI == E_BF16T2) {
          if (g.e0) v += g.beta * b2f(((const ush*)g.e0)[(long)bz*g.sD + (long)grow*g.ldo0 + gcol]);
          ush hv = f2b(v);
          ((ush*)g.o0)[(long)bz*g.sO + (long)grow*g.ldo0 + gcol] = hv;
          tb[lrow*65 + lcol] = hv;
        } else if constexpr (EPI == E_SPLIT) {
          if (g.e0) v += g.beta * ((const float*)g.e0)[(long)bz*g.sD + (long)grow*g.ldo0 + gcol];
          if (g.o0) ((float*)g.o0)[(long)bz*g.sO + (long)grow*g.ldo0 + gcol] = v;
          ush hv = f2b(v);
          ush lv = f2b(v - b2f(hv));
          ((ush*)g.o1)[(long)bz*g.sO + (long)grow*g.ldo0 + gcol] = hv;
          ((ush*)g.o2)[(long)bz*g.sO + (long)grow*g.ldo0 + gcol] = lv;
          if (TRX) tb[lrow*65 + lcol] = (uint32)hv | ((uint32)lv<<16);
        } else if constexpr (EPI == E_QW) {
          ush hv = f2b(v);
          ((ush*)g.o0)[(long)bz*g.sO + (long)grow*g.ldo0 + gcol] = hv;
          tb[lrow*65 + lcol] = hv;
        } else if constexpr (EPI == E_PRE) {
          v += ((const float*)g.e0)[gcol];
          v = v > 0.f ? v : 0.f;
          ((ush*)g.o0)[(long)grow*g.ldo0 + gcol] = f2b(v);
        } else if constexpr (EPI == E_GH) {
          if (gcol < 512) {
            float h = v - b2f(((const ush*)g.e0)[(long)grow*g.ldE + gcol]);
            ush hb = f2b(h);
            ((ush*)g.o0)[(long)grow*512 + gcol] = hb;
            if (g.o2) ((ush*)g.o2)[(long)grow*4096 + gcol] = hb;
          } else {
            float y = b2f(((const ush*)g.e1)[(long)grow*512 + (gcol-512)]) - v;
            ((ush*)g.o1)[(long)grow*4096 + (gcol-512)] = f2b(y);
          }
        } else if constexpr (EPI == E_OUT) {
          float o = 0.5f*(10.1f*((const float*)g.e0)[(long)grow*1024 + gcol] + v)
                  + ((const float*)g.e1)[gcol];
          ((float*)g.o0)[(long)grow*1024 + gcol] = o;
        }
      }

  // ---------------- transposed writes (coalesced via LDS) ------------------
  if constexpr (TRX) {
    __syncthreads();
    const int tr  = t >> 2;     // transposed row = original col
    const int seg = t & 3;
    uint32 vals[16];
    #pragma unroll
    for (int u=0;u<16;u++) vals[u] = tb[(seg*16+u)*65 + tr];
    ush hb[16] __attribute__((aligned(16)));
    ush lb[16] __attribute__((aligned(16)));
    #pragma unroll
    for (int u=0;u<16;u++){ hb[u] = (ush)(vals[u]&0xffffu); lb[u] = (ush)(vals[u]>>16); }
    const long bT = (long)bz*g.sO + (long)(n0+tr)*g.ldo1 + m0 + seg*16;
    if constexpr (EPI == E_BF16T2) {
      st16((ush*)g.o1 + bT, hb);
    } else if constexpr (EPI == E_SPLIT) {
      if (g.o3) { st16((ush*)g.o3 + bT, hb); st16((ush*)g.o4 + bT, lb); }
    } else if constexpr (EPI == E_QW) {
      st16((ush*)g.o1 + bT, hb);
    }
  }
}

// ---------------- fused phase-4 NS chain (persistent, grid-barrier) --------
// 9 iterations of { Yh = (M X)^T ; X' = 2X - X Y^T } on Q (1024^2) + 8 R
// (512^2).  768 blocks (3/CU @ 32KB LDS, guaranteed co-resident), job map
// [Q,R,R] per block triple.  Two-level device-scope barrier.
__global__ __launch_bounds__(256) void ns_fused(
    const ush* __restrict__ Mh, ush* XhA, ush* XThA, ush* XhB, ush* XThB,
    ush* Yh, uint32* bar, int iters)
{
  constexpr int PANEL = 4096;   // ush (8 KB): 64x32 A + 64x32 B
  constexpr int NBUF  = 4;
  __shared__ ush smem[NBUF*PANEL] __attribute__((aligned(16)));   // 32 KB
  uint32* tb = (uint32*)smem;

  const int b = blockIdx.x;
  const int tri = b/3, rph = b - tri*3;
  int m0, n0, ld, K; long base;
  if (rph == 0){           // Q job (256 of them)
    m0 = (tri>>4)<<6; n0 = (tri&15)<<6; base = 0; ld = 1024; K = 1024;
  } else {                 // R jobs (512 of them)
    const int rj = tri*2 + rph - 1;      // 0..511
    const int z = rj>>6, idx = rj&63;
    m0 = (idx>>3)<<6; n0 = (idx&7)<<6;
    base = 1048576l + (long)z*262144l; ld = 512; K = 512;
  }

  const int t = threadIdx.x, lane = t&63, wave = t>>6;
  const int wm = (wave>>1)*32, wn = (wave&1)*32;
  const int sr = lane>>2, scg = lane&3;
  const int fr = lane&15, cc = lane>>4;

  int barno = 0;
  auto gbar = [&](){
    __syncthreads();
    if (t == 0){
      const int grp = b >> 5;                       // 24 groups of 32
      uint32 v = __hip_atomic_fetch_add(&bar[64 + grp*32], 1u,
                    __ATOMIC_RELEASE, __HIP_MEMORY_SCOPE_AGENT);
      if (v == 31u){
        __hip_atomic_store(&bar[64 + grp*32], 0u,
                    __ATOMIC_RELAXED, __HIP_MEMORY_SCOPE_AGENT);
        uint32 r = __hip_atomic_fetch_add(&bar[16], 1u,
                    __ATOMIC_ACQ_REL, __HIP_MEMORY_SCOPE_AGENT);
        if (r == 23u){
          __hip_atomic_store(&bar[16], 0u,
                    __ATOMIC_RELAXED, __HIP_MEMORY_SCOPE_AGENT);
          __hip_atomic_fetch_add(&bar[32], 1u,
                    __ATOMIC_RELEASE, __HIP_MEMORY_SCOPE_AGENT);
        }
      }
      while ((int)__hip_atomic_load(&bar[32],
                    __ATOMIC_ACQUIRE, __HIP_MEMORY_SCOPE_AGENT) <= barno)
        __builtin_amdgcn_s_sleep(2);
      __threadfence();
    }
    __syncthreads();
    ++barno;
  };

  auto run_gemm = [&](const ush* A, const ush* B, bool g2,
                      const ush* e0, ush* o0, ush* oT){
    f4v acc[2][2];
    #pragma unroll
    for (int i=0;i<2;i++)
      #pragma unroll
      for (int j=0;j<2;j++) acc[i][j] = f4v{0.f,0.f,0.f,0.f};
    auto STAGE = [&](int k0, int nb){
      ush* dA = smem + nb*PANEL;
      ush* dB = dA + 2048;
      const int lr = wave*16 + sr;
      const int gc = scg ^ ((lr>>1)&3);
      gload16(A + (long)(m0+lr)*ld + k0 + gc*8, &dA[lr*32]);
      gload16(B + (long)(n0+lr)*ld + k0 + gc*8, &dB[lr*32]);
    };
    STAGE(0,0); STAGE(32,1);
    int cur = 0;
    for (int k0 = 0; k0 < K; k0 += 32){
      const int rem = ((K - k0) >> 5) - 1;
      if (rem >= 2){ STAGE(k0+64, (cur+2)&3);
        asm volatile("s_waitcnt vmcnt(4)" ::: "memory"); }
      else if (rem == 1){ asm volatile("s_waitcnt vmcnt(2)" ::: "memory"); }
      else { asm volatile("s_waitcnt vmcnt(0)" ::: "memory"); }
      __builtin_amdgcn_sched_barrier(0);
      __builtin_amdgcn_s_barrier();
      __builtin_amdgcn_sched_barrier(0);
      const ush* rA = smem + cur*PANEL;
      const ush* rB = rA + 2048;
      s8v af[2], bf_[2];
      #pragma unroll
      for (int i=0;i<2;i++){ const int row = wm+i*16+fr;
        af[i] = *(const s8v*)&rA[row*32 + ((cc ^ ((row>>1)&3))<<3)]; }
      #pragma unroll
      for (int j=0;j<2;j++){ const int row = wn+j*16+fr;
        bf_[j] = *(const s8v*)&rB[row*32 + ((cc ^ ((row>>1)&3))<<3)]; }
      #pragma unroll
      for (int i=0;i<2;i++)
        #pragma unroll
        for (int j=0;j<2;j++)
          acc[i][j] = __builtin_amdgcn_mfma_f32_16x16x32_bf16(af[i],bf_[j],acc[i][j],0,0,0);
      cur = (cur+1)&3;
    }
    if (g2) __syncthreads();   // tb aliases staging bufs
    #pragma unroll
    for (int i=0;i<2;i++)
      #pragma unroll
      for (int j=0;j<2;j++)
        #pragma unroll
        for (int r=0;r<4;r++){
          const int lrow = wm + i*16 + ((lane>>4)<<2) + r;
          const int lcol = wn + j*16 + fr;
          const long off = (long)(m0+lrow)*ld + n0 + lcol;
          if (!g2){
            o0[off] = f2b(acc[i][j][r]);
          } else {
            float v = 2.f*b2f(e0[off]) - acc[i][j][r];
            ush hv = f2b(v);
            o0[off] = hv;
            tb[lrow*65 + lcol] = hv;
          }
        }
    if (g2){
      __syncthreads();
      const int tr = t>>2, seg = t&3;
      uint32 vals[16];
      #pragma unroll
      for (int u=0;u<16;u++) vals[u] = tb[(seg*16+u)*65 + tr];
      ush hb[16] __attribute__((aligned(16)));
      #pragma unroll
      for (int u=0;u<16;u++) hb[u] = (ush)vals[u];
      st16(oT + (long)(n0+tr)*ld + m0 + seg*16, hb);
    }
  };

  ush* X[2]  = {XhA, XhB};
  ush* XT[2] = {XThA, XThB};
  int cur = 0;
  for (int it = 0; it < iters; ++it){
    // GEMM1: Yh = (M X)^T  == XT[cur] * Mh^T
    run_gemm(XT[cur] + base, Mh + base, false, nullptr, Yh + base, nullptr);
    gbar();
    // GEMM2: X[nxt] = 2 X[cur] - X[cur] * Yh^T  (+ transposed copy)
    run_gemm(X[cur] + base, Yh + base, true, X[cur] + base,
             X[cur^1] + base, XT[cur^1] + base);
    if (it != iters-1) gbar();
    cur ^= 1;
  }
}

// ------------------------------ small kernels ------------------------------

__global__ __launch_bounds__(256) void k_norms(const float* __restrict__ Fq,
    const float* __restrict__ Fr0, const float* __restrict__ Frr, float* s2){
  const int y = blockIdx.y;
  const float* p; long cnt4;
  if (y==0){ p=Fq; cnt4=1048576l; }
  else if (y==1){ p=Fr0; cnt4=65536l; }
  else { p=Frr + (long)(y-2)*524288; cnt4=131072l; }
  float s = 0.f;
  for (long i = (long)blockIdx.x*256 + threadIdx.x; i < cnt4; i += (long)gridDim.x*256){
    float4 v = ((const float4*)p)[i];
    s += v.x*v.x + v.y*v.y + v.z*v.z + v.w*v.w;
  }
  #pragma unroll
  for (int o=32;o>0;o>>=1) s += __shfl_down(s, o, 64);
  __shared__ float red[4];
  if ((threadIdx.x & 63)==0) red[threadIdx.x>>6] = s;
  __syncthreads();
  if (threadIdx.x==0) atomicAdd(&s2[y], red[0]+red[1]+red[2]+red[3]);
}

__global__ void k_scales(const float* s2, const float* fq, const float* fr, float* sc){
  int t = threadIdx.x;
  if (t < 9){
    float v = (t==0)? fq[0] : fr[t-1];
    sc[t] = v / (sqrtf(s2[t]) + 1e-5f);
  }
}

// tiled build of V (3072x1024, z=0) and Wr (7x512x512, z=1..7), hi/lo + transpose
__global__ __launch_bounds__(256) void k_buildT(const float* __restrict__ Fq,
    const float* __restrict__ Frr, const float* sc,
    ush* Vh, ush* Vl, ush* Vth, ush* Vtl,
    ush* Wrh, ush* Wrl, ush* WrTh, ush* WrTl){
  __shared__ uint32 tb[64*65];
  const int z = blockIdx.z;
  const int r = threadIdx.x >> 2;
  const int cs = (threadIdx.x & 3)*16;
  ush hh[16] __attribute__((aligned(16)));
  ush ll[16] __attribute__((aligned(16)));
  if (z==0){
    const long r0 = (long)blockIdx.y*64, c0 = (long)blockIdx.x*64;
    const float s = sc[0];
    const float* src = &Fq[(1024+r0+r)*1024 + c0 + cs];
    #pragma unroll
    for (int u=0;u<16;u++){
      float v = s*src[u];
      ush h = f2b(v); ush l = f2b(v - b2f(h));
      hh[u]=h; ll[u]=l;
      tb[r*65 + cs + u] = (uint32)h | ((uint32)l<<16);
    }
    st16(&Vh[(r0+r)*1024 + c0 + cs], hh);
    st16(&Vl[(r0+r)*1024 + c0 + cs], ll);
    __syncthreads();
    const int tr = threadIdx.x>>2, seg = threadIdx.x&3;
    #pragma unroll
    for (int u=0;u<16;u++){
      uint32 v = tb[(seg*16+u)*65 + tr];
      hh[u]=(ush)(v&0xffffu); ll[u]=(ush)(v>>16);
    }
    st16(&Vth[(c0+tr)*3072 + r0 + seg*16], hh);
    st16(&Vtl[(c0+tr)*3072 + r0 + seg*16], ll);
  } else {
    if (blockIdx.x>=8 || blockIdx.y>=8) return;
    const int k = z-1;
    const long r0 = (long)blockIdx.y*64, c0 = (long)blockIdx.x*64;
    const float s = sc[2+k];
    const float* src = &Frr[(long)k*524288 + (r0+r)*1024 + 512 + c0 + cs];
    #pragma unroll
    for (int u=0;u<16;u++){
      float v = s*src[u];
      ush h = f2b(v); ush l = f2b(v - b2f(h));
      hh[u]=h; ll[u]=l;
      tb[r*65 + cs + u] = (uint32)h | ((uint32)l<<16);
    }
    st16(&Wrh[(long)k*262144 + (r0+r)*512 + c0 + cs], hh);
    st16(&Wrl[(long)k*262144 + (r0+r)*512 + c0 + cs], ll);
    __syncthreads();
    const int tr = threadIdx.x>>2, seg = threadIdx.x&3;
    #pragma unroll
    for (int u=0;u<16;u++){
      uint32 v = tb[(seg*16+u)*65 + tr];
      hh[u]=(ush)(v&0xffffu); ll[u]=(ush)(v>>16);
    }
    st16(&WrTh[(long)k*262144 + (c0+tr)*512 + r0 + seg*16], hh);
    st16(&WrTl[(long)k*262144 + (c0+tr)*512 + r0 + seg*16], ll);
  }
}

// tiled assembly of M = I + A (hi/lo) and M^T: z=0 Q (16x16 tiles), z=1..8 R (8x8)
__global__ __launch_bounds__(256) void k_asmT(const float* __restrict__ Fq,
    const float* __restrict__ Fr0, const float* __restrict__ Frr,
    const float* sc, const float* __restrict__ PP,
    ush* Mh, ush* Ml, ush* MTh, ush* MTl){
  __shared__ uint32 tb[64*65];
  const int z = blockIdx.z;
  const int r = threadIdx.x >> 2;
  const int cs = (threadIdx.x & 3)*16;
  const long ROFF = 1048576l, RS = 262144l;
  long r0 = (long)blockIdx.y*64, c0 = (long)blockIdx.x*64;
  const float* dsrc; const float* msrc; const float* psrc = nullptr;
  float s; long obase; long old_; float sgn;
  if (z==0){
    s = sc[0]; sgn = 1.f;
    dsrc = &Fq[(r0+r)*1024 + c0 + cs];
    msrc = &Fq[(c0+r)*1024 + r0 + cs];
    psrc = &PP[(r0+r)*1024 + c0 + cs];
    obase = 0; old_ = 1024;
  } else {
    if (blockIdx.x>=8 || blockIdx.y>=8) return;
    const int b = z-1;
    if (b==0){
      s = sc[1]; sgn = 1.f;
      dsrc = &Fr0[(r0+r)*512 + c0 + cs];
      msrc = &Fr0[(c0+r)*512 + r0 + cs];
    } else {
      s = sc[1+b]; sgn = -1.f;   // a = s*(W[c][r]-W[r][c]) = s*(mirror-direct)
      const float* W = Frr + (long)(b-1)*524288;
      dsrc = &W[(r0+r)*1024 + c0 + cs];
      msrc = &W[(c0+r)*1024 + r0 + cs];
      psrc = &PP[ROFF + (long)(b-1)*RS + (r0+r)*512 + c0 + cs];
    }
    obase = ROFF + (long)b*RS; old_ = 512;
  }
  // stage mirror tile (float bits)
  #pragma unroll
  for (int u=0;u<16;u++) tb[r*65 + cs + u] = __float_as_uint(msrc[u]);
  __syncthreads();
  ush hh[16] __attribute__((aligned(16)));
  ush ll[16] __attribute__((aligned(16)));
  #pragma unroll
  for (int u=0;u<16;u++){
    const int c = cs + u;
    float mir = __uint_as_float(tb[c*65 + r]);
    float a = sgn * s * (dsrc[u] - mir);
    if (psrc) a += psrc[u];
    float m = ((r0 + r == c0 + c) ? 1.f : 0.f) + a;
    ush h = f2b(m); ush l = f2b(m - b2f(h));
    hh[u]=h; ll[u]=l;
  }
  st16(&Mh[obase + (r0+r)*old_ + c0 + cs], hh);
  st16(&Ml[obase + (r0+r)*old_ + c0 + cs], ll);
  __syncthreads();
  #pragma unroll
  for (int u=0;u<16;u++) tb[r*65 + cs + u] = (uint32)hh[u] | ((uint32)ll[u]<<16);
  __syncthreads();
  const int tr = threadIdx.x>>2, seg = threadIdx.x&3;
  #pragma unroll
  for (int u=0;u<16;u++){
    uint32 v = tb[(seg*16+u)*65 + tr];
    hh[u]=(ush)(v&0xffffu); ll[u]=(ush)(v>>16);
  }
  st16(&MTh[obase + (c0+tr)*old_ + r0 + seg*16], hh);
  st16(&MTl[obase + (c0+tr)*old_ + r0 + seg*16], ll);
}

__global__ __launch_bounds__(256) void k_rowabs(const float* __restrict__ T2, float* bmax){
  const int y = blockIdx.y;
  const float* row; int n;
  if (y==0){ row = T2 + (long)blockIdx.x*1024; n = 1024; }
  else { if (blockIdx.x >= 512) return;
         row = T2 + 1048576l + (long)(y-1)*262144 + (long)blockIdx.x*512; n = 512; }
  float s=0.f;
  for (int i=threadIdx.x;i<n;i+=256) s += fabsf(row[i]);
  #pragma unroll
  for (int o=32;o>0;o>>=1) s += __shfl_down(s,o,64);
  __shared__ float red[4];
  if ((threadIdx.x&63)==0) red[threadIdx.x>>6]=s;
  __syncthreads();
  if (threadIdx.x==0){
    float tot = red[0]+red[1]+red[2]+red[3];
    atomicMax((unsigned int*)&bmax[y], __float_as_uint(tot));
  }
}

__global__ void k_makec(const float* bmax, float* cvl){
  int t=threadIdx.x;
  if (t<9){
    float bnd = sqrtf(fmaxf(bmax[t], 1.f));   // >= sigma_max(M)^2
    cvl[t] = 1.9f/(1.f + bnd);
  }
}

__global__ __launch_bounds__(256) void k_initX(const ush* __restrict__ Mh,
    const ush* __restrict__ MTh, const float* cvl, ush* Xh, ush* XTh){
  long i = (long)blockIdx.x*256 + threadIdx.x;
  int b = (i < 1048576l) ? 0 : 1 + (int)((i - 1048576l) >> 18);
  float c = cvl[b];
  Xh[i]  = f2b(c * b2f(MTh[i]));
  XTh[i] = f2b(c * b2f(Mh[i]));
}

__global__ __launch_bounds__(256) void k_promote(const ush* __restrict__ Xh,
    float* Xf, ush* Xl, ush* XTl){
  long i = (long)blockIdx.x*256 + threadIdx.x;
  Xf[i] = b2f(Xh[i]);
  Xl[i] = 0; XTl[i] = 0;
}

// tops: 2X - I, tiled, value + transposed copy.  z=0 Q (16x16), z=1..8 R (8x8)
__global__ __launch_bounds__(256) void k_topT(const ush* __restrict__ Xh, const ush* __restrict__ Xl,
    ush* Qb, ush* QTb, ush* RK, ush* RKT){
  __shared__ uint32 tb[64*65];
  const int z = blockIdx.z;
  const int r = threadIdx.x >> 2;
  const int cs = (threadIdx.x & 3)*16;
  const long ROFF = 1048576l, RS = 262144l;
  long r0 = (long)blockIdx.y*64, c0 = (long)blockIdx.x*64;
  ush hh[16] __attribute__((aligned(16)));
  if (z==0){
    const long base = (r0+r)*1024 + c0 + cs;
    #pragma unroll
    for (int u=0;u<16;u++){
      float v = 2.f*(b2f(Xh[base+u]) + b2f(Xl[base+u])) - ((r0+r == c0+cs+u)?1.f:0.f);
      hh[u] = f2b(v);
      tb[r*65 + cs + u] = hh[u];
    }
    st16(&Qb[(r0+r)*1024 + c0 + cs], hh);
    __syncthreads();
    const int tr = threadIdx.x>>2, seg = threadIdx.x&3;
    #pragma unroll
    for (int u=0;u<16;u++) hh[u] = (ush)tb[(seg*16+u)*65 + tr];
    st16(&QTb[(c0+tr)*4096 + r0 + seg*16], hh);
  } else {
    if (blockIdx.x>=8 || blockIdx.y>=8) return;
    const int b = z-1;
    const long base = ROFF + (long)b*RS + (r0+r)*512 + c0 + cs;
    #pragma unroll
    for (int u=0;u<16;u++){
      float v = 2.f*(b2f(Xh[base+u]) + b2f(Xl[base+u])) - ((r0+r == c0+cs+u)?1.f:0.f);
      hh[u] = f2b(v);
      tb[r*65 + cs + u] = hh[u];
    }
    st16(&RKT[(long)b*524288 + (r0+r)*512 + c0 + cs], hh);
    __syncthreads();
    const int tr = threadIdx.x>>2, seg = threadIdx.x&3;
    #pragma unroll
    for (int u=0;u<16;u++) hh[u] = (ush)tb[(seg*16+u)*65 + tr];
    st16(&RK[(long)b*524288 + (c0+tr)*1024 + r0 + seg*16], hh);
  }
}

__global__ __launch_bounds__(256) void k_f2bf(const float* __restrict__ in, ush* __restrict__ o){
  long i = ((long)blockIdx.x*256 + threadIdx.x)*8;
  float4 a = *(const float4*)(in+i);
  float4 b = *(const float4*)(in+i+4);
  ush u[8] __attribute__((aligned(16)));
  u[0]=f2b(a.x);u[1]=f2b(a.y);u[2]=f2b(a.z);u[3]=f2b(a.w);
  u[4]=f2b(b.x);u[5]=f2b(b.y);u[6]=f2b(b.z);u[7]=f2b(b.w);
  *(int4*)(o+i) = *(const int4*)u;
}

// ------------------------------ host driver -------------------------------

static GA mk(const ush* Ah, const ush* Al, long lda,
             const ush* Bh, const ush* Bl, long ldb,
             int K, int M, int N, float alpha){
  GA g{}; g.ksplit=1<<30; g.A0h=Ah; g.A0l=Al; g.lda0=lda;
  g.Bh=Bh; g.Bl=Bl; g.ldb=ldb; g.K=K; g.M=M; g.N=N; g.alpha=alpha; g.beta=0.f;
  return g;
}

extern "C" void kernel_launch(void* const* d_in, const int* in_sizes, int n_in,
                              void* d_out, int out_size, void* d_ws, size_t ws_size,
                              hipStream_t stream)
{
  (void)in_sizes; (void)n_in; (void)out_size; (void)ws_size;
  const float* x   = (const float*)d_in[0];
  const float* Fq  = (const float*)d_in[1];
  const float* fqp = (const float*)d_in[2];
  const float* by  = (const float*)d_in[3];
  const float* Fr0 = (const float*)d_in[4];
  const float* Frr = (const float*)d_in[5];
  const float* frp = (const float*)d_in[6];
  const float* bp  = (const float*)d_in[7];
  float* out = (float*)d_out;

  const float SQG = sqrtf(10.0f - 0.1f);
  const float SQ2 = sqrtf(2.0f);
  const long UN = 3145728l;
  const long ROFF = 1048576l, RS = 262144l;

  char* base = (char*)d_ws;
  size_t off = 0;
  auto alloc = [&](size_t bytes)->char*{
    char* p = base + off; off = (off + bytes + 255) & ~(size_t)255; return p;
  };

  // ---- persistent ----
  ush* Qb  = (ush*)alloc(4194304l*2);
  ush* QTb = (ush*)alloc(4194304l*2);
  ush* RK  = (ush*)alloc(4194304l*2);
  ush* RKT = (ush*)alloc(4194304l*2);
  ush* xbf = (ush*)alloc(8388608l*2);
  float* scal = (float*)alloc(256*4);
  float* s2   = scal;
  float* bmax = scal + 16;
  float* cvl  = scal + 32;
  float* sc   = scal + 48;
  uint32* bar = (uint32*)alloc(4096);

  const size_t scratch0 = off;
  ush* Vh   = (ush*)alloc(UN*2);
  ush* Vl   = (ush*)alloc(UN*2);
  ush* Vth  = (ush*)alloc(UN*2);
  ush* Vtl  = (ush*)alloc(UN*2);
  ush* Wrh  = (ush*)alloc(1835008l*2);
  ush* Wrl  = (ush*)alloc(1835008l*2);
  ush* WrTh = (ush*)alloc(1835008l*2);
  ush* WrTl = (ush*)alloc(1835008l*2);
  float* PPf = (float*)alloc(UN*4);
  ush* Mh  = (ush*)alloc(UN*2);
  ush* Ml  = (ush*)alloc(UN*2);
  ush* MTh = (ush*)alloc(UN*2);
  ush* MTl = (ush*)alloc(UN*2);
  ush* Sh  = (ush*)alloc(UN*2);
  ush* XhA = (ush*)alloc(UN*2);
  ush* XhB = (ush*)alloc(UN*2);
  ush* XlA = (ush*)alloc(UN*2);
  ush* XlB = (ush*)alloc(UN*2);
  ush* XThA = (ush*)alloc(UN*2);
  ush* XThB = (ush*)alloc(UN*2);
  ush* XTlA = (ush*)alloc(UN*2);
  ush* XTlB = (ush*)alloc(UN*2);
  float* XfA = (float*)alloc(UN*4);
  float* XfB = (float*)alloc(UN*4);
  ush* Yh  = (ush*)alloc(UN*2);
  ush* Yl  = (ush*)alloc(UN*2);

  ush* Xh[2]  = {XhA, XhB};
  ush* Xl[2]  = {XlA, XlB};
  ush* XTh[2] = {XThA, XThB};
  ush* XTl[2] = {XTlA, XTlB};
  float* Xf[2] = {XfA, XfB};

  dim3 B256(256);
  GA ga{}, gr{};

  // ---- phase 0: norms & scales ----
  (void)hipMemsetAsync(scal, 0, 1024, stream);
  (void)hipMemsetAsync(bar, 0, 4096, stream);
  k_norms<<<dim3(256,9),B256,0,stream>>>(Fq, Fr0, Frr, s2);
  k_scales<<<1,16,0,stream>>>(s2, fqp, frp, sc);

  // ---- phase 1: build V / Wr (tiled, coalesced) ----
  k_buildT<<<dim3(16,48,8),B256,0,stream>>>(Fq, Frr, sc, Vh,Vl,Vth,Vtl, Wrh,Wrl,WrTh,WrTl);

  // PQ = V^T V ; PR_k = Wr Wr^T (split) -> PPf
  ga = mk(Vth,Vtl,3072, Vth,Vtl,3072, 3072,1024,1024, 1.f); ga.o0=PPf; ga.ldo0=1024;
  gr = mk(Wrh,Wrl,512, Wrh,Wrl,512, 512,512,512, 1.f);
  gr.sA=RS; gr.sB=RS; gr.o0=PPf+ROFF; gr.sO=RS; gr.ldo0=512;
  gemm_k<64,64,E_F32,true,false><<<dim3(16,16,8),B256,0,stream>>>(ga,gr,1);

  // ---- phase 2: assemble M, M^T (tiled) ----
  k_asmT<<<dim3(16,16,9),B256,0,stream>>>(Fq, Fr0, Frr, sc, PPf, Mh,Ml,MTh,MTl);

  // ---- phase 3: bound: S = M*M^T (bf16), S^2 (f32), rowabs, c, X0 ----
  ga = mk(Mh,nullptr,1024, Mh,nullptr,1024, 1024,1024,1024, 1.f); ga.o0=Sh; ga.ldo0=1024;
  gr = mk(Mh+ROFF,nullptr,512, Mh+ROFF,nullptr,512, 512,512,512, 1.f);
  gr.sA=RS; gr.sB=RS; gr.o0=Sh+ROFF; gr.sO=RS; gr.ldo0=512;
  gemm_k<64,64,E_BF16,false,false><<<dim3(16,16,9),B256,0,stream>>>(ga,gr,1);

  ga = mk(Sh,nullptr,1024, Sh,nullptr,1024, 1024,1024,1024, 1.f); ga.o0=PPf; ga.ldo0=1024;
  gr = mk(Sh+ROFF,nullptr,512, Sh+ROFF,nullptr,512, 512,512,512, 1.f);
  gr.sA=RS; gr.sB=RS; gr.o0=PPf+ROFF; gr.sO=RS; gr.ldo0=512;
  gemm_k<64,64,E_F32,false,false><<<dim3(16,16,9),B256,0,stream>>>(ga,gr,1);
  k_rowabs<<<dim3(1024,9),B256,0,stream>>>(PPf, bmax);
  k_makec<<<1,16,0,stream>>>(bmax, cvl);
  k_initX<<<12288,B256,0,stream>>>(Mh, MTh, cvl, Xh[0], XTh[0]);

  // ---- phase 4: coupled NS bf16 (9 iters) -- FUSED persistent kernel ----
  ns_fused<<<768,B256,0,stream>>>(Mh, XhA, XThA, XhB, XThB, Yh, bar, 9);
  int cur = 1;   // 9 iterations: final X in buffer B

  // ---- phase 5: promote + 2 split-precision NS iters ----
  k_promote<<<12288,B256,0,stream>>>(Xh[cur], Xf[cur], Xl[cur], XTl[cur]);
  for (int it=0; it<2; ++it){
    int nxt = cur^1;
    ga = mk(XTh[cur],XTl[cur],1024, Mh,Ml,1024, 1024,1024,1024, 1.f);
    ga.o1=Yh; ga.o2=Yl; ga.ldo0=1024;
    gr = mk(XTh[cur]+ROFF,XTl[cur]+ROFF,512, Mh+ROFF,Ml+ROFF,512, 512,512,512, 1.f);
    gr.sA=RS; gr.sB=RS; gr.o1=Yh+ROFF; gr.o2=Yl+ROFF; gr.sO=RS; gr.ldo0=512;
    gemm_k<64,64,E_SPLIT,true,false><<<dim3(16,16,9),B256,0,stream>>>(ga,gr,1);

    ga = mk(Xh[cur],Xl[cur],1024, Yh,Yl,1024, 1024,1024,1024, -1.f);
    ga.beta=2.f; ga.e0=Xf[cur];
    ga.o0=Xf[nxt]; ga.o1=Xh[nxt]; ga.o2=Xl[nxt]; ga.o3=XTh[nxt]; ga.o4=XTl[nxt];
    ga.ldo0=1024; ga.ldo1=1024;
    gr = mk(Xh[cur]+ROFF,Xl[cur]+ROFF,512, Yh+ROFF,Yl+ROFF,512, 512,512,512, -1.f);
    gr.beta=2.f; gr.e0=Xf[cur]+ROFF; gr.sD=RS;
    gr.sA=RS; gr.sB=RS; gr.sO=RS;
    gr.o0=Xf[nxt]+ROFF; gr.o1=Xh[nxt]+ROFF; gr.o2=Xl[nxt]+ROFF;
    gr.o3=XTh[nxt]+ROFF; gr.o4=XTl[nxt]+ROFF;
    gr.ldo0=512; gr.ldo1=512;
    gemm_k<64,64,E_SPLIT,true,true><<<dim3(16,16,9),B256,0,stream>>>(ga,gr,1);
    cur = nxt;
  }

  // ---- phase 6: tops = 2X - I (tiled) ; bottoms = -2*V*X (QW + LDS transpose) ----
  k_topT<<<dim3(16,16,9),B256,0,stream>>>(Xh[cur], Xl[cur], Qb, QTb, RK, RKT);

  ga = mk(Vh,Vl,1024, XTh[cur],XTl[cur],1024, 1024,3072,1024, -2.f);
  ga.o0=Qb + 1048576l; ga.ldo0=1024; ga.o1=QTb + 1024; ga.ldo1=4096;
  gr = mk(WrTh,WrTl,512, XTh[cur]+ROFF+RS, XTl[cur]+ROFF+RS, 512, 512,512,512, -2.f);
  gr.sA=RS; gr.sB=RS; gr.sO=524288;
  gr.o0=RKT + 524288 + 262144; gr.ldo0=512;
  gr.o1=RK + 524288 + 512; gr.ldo1=1024;
  gemm_k<64,64,E_QW,true,true><<<dim3(16,48,8),B256,0,stream>>>(ga,gr,1);

  // ---- main-path overlay buffers ----
  off = scratch0;
  ush* xh  = (ush*)alloc(33554432l*2);
  ush* yh  = (ush*)alloc(33554432l*2);
  ush* pre = (ush*)alloc(4194304l*2);
  ush* h0  = (ush*)alloc(4194304l*2);
  ush* h1  = (ush*)alloc(4194304l*2);

  // ---- phase 7: main chain ----
  k_f2bf<<<4096,B256,0,stream>>>(x, xbf);
  ga = mk(xbf,nullptr,1024, Qb,nullptr,1024, 1024,8192,4096, SQG);
  ga.o0=xh; ga.ldo0=4096;
  gemm_k<128,128,E_BF16,false,false><<<dim3(32,64,1),B256,0,stream>>>(ga,ga,1);

  for (int k=0;k<8;++k){
    ush* hprev = (k==0)? nullptr : (((k-1)&1) ? h1 : h0);
    ush* hnew  = (k&1) ? h1 : h0;
    GA gp_ = mk(xh + (long)k*512, nullptr, 4096,
                (k==0)? RKT : RK + (long)k*524288, nullptr, (k==0)?512:1024,
                (k==0)?512:1024, 8192, 512, SQ2);
    gp_.ksplit = 512; gp_.A1h = hprev; gp_.lda1 = 512;
    gp_.e0 = bp + (long)k*512; gp_.o0 = pre; gp_.ldo0 = 512;
    gemm_k<128,64,E_PRE,false,false><<<dim3(8,64,1),B256,0,stream>>>(gp_,gp_,1);

    GA gg = mk(pre, nullptr, 512,
               (k==0)? RK : RKT + (long)k*524288, nullptr, (k==0)?1024:512,
               512, 8192, (k==0)?512:1024, SQ2);
    gg.e0 = xh + (long)k*512; gg.ldE = 4096;
    gg.e1 = hprev;
    gg.o0 = hnew;
    gg.o1 = (k>=1)? (void*)(yh + (long)(k-1)*512) : nullptr;
    gg.o2 = (k==7)? (void*)(yh + 3584) : nullptr;
    if (k==0) gemm_k<128,64,E_GH,false,false><<<dim3(8,64,1),B256,0,stream>>>(gg,gg,1);
    else      gemm_k<128,128,E_GH,false,false><<<dim3(8,64,1),B256,0,stream>>>(gg,gg,1);
  }

  // out = 0.5*(10.1*x + sqrt_gam*(yh@Q)) + by
  ga = mk(yh,nullptr,4096, QTb,nullptr,4096, 4096,8192,1024, SQG);
  ga.e0=x; ga.e1=by; ga.o0=out; ga.ldo0=1024;
  gemm_k<128,128,E_OUT,false,false><<<dim3(8,64,1),B256,0,stream>>>(ga,ga,1);
}

// Round 8
// 2070.048 us; speedup vs baseline: 1.5421x; 1.5421x over previous
//
#include <hip/hip_runtime.h>
#include <math.h>

// ---------------------------------------------------------------------------
// MonLipLayer forward on MI355X.  R12 = R11 de-risked: R11 launched ns_fused
// at exactly-full 1024 blocks ASSUMING 4/CU co-residency -- a spin-barrier
// deadlock if occupancy is 3/CU (likely cause of the R11 hang/timeout).
//  (a) Host occupancy query (graph-capture-safe) -> grid = min(1024,
//      256*maxBlocksPerCU), fallback 768 (proven resident in R10).
//  (b) Jobs (1024, perfectly balanced) decoupled from grid via job-striding
//      with per-job __syncthreads (LDS reuse safe: drains vmcnt+lgkm).
//  (c) Tree barrier generalized to ngroups = gridDim.x/32.
// R11: monotone tree barrier (no resets, <=32 spinners/address), balanced
// Q-half (32x64,K=1024) + R (64x64,K=512) jobs.  R7/R8: counted-vmcnt
// pipeline, depth-2 <=8KB panels, vectorized k_norms.
// Math unchanged.  C = alpha * A(MxK,row) * Bt(NxK,row)^T + beta * D.
// ---------------------------------------------------------------------------

using s8v = __attribute__((ext_vector_type(8))) short;   // 8 x bf16
using f4v = __attribute__((ext_vector_type(4))) float;
typedef unsigned short ush;
typedef unsigned int uint32;

#define DEV __device__ __forceinline__

DEV float b2f(ush u){ union{unsigned int i; float f;} v; v.i = ((unsigned int)u)<<16; return v.f; }
DEV ush f2b(float f){
  union{float f; unsigned int i;} v; v.f = f;
  unsigned int u = v.i;
  return (ush)((u + 0x7fffu + ((u>>16)&1u)) >> 16);
}

typedef __attribute__((address_space(1))) void gvoid;
typedef __attribute__((address_space(3))) void lvoid;
DEV void gload16(const void* g, void* l){
  __builtin_amdgcn_global_load_lds((gvoid*)g, (lvoid*)l, 16, 0, 0);
}

DEV void st16(ush* dst, const ush* a){
  *(int4*)dst = *(const int4*)a; *(int4*)(dst+8) = *(const int4*)(a+8);
}

struct GA {
  const ush *A0h, *A0l; long lda0;
  const ush *A1h, *A1l; long lda1; int ksplit;
  const ush *Bh, *Bl; long ldb;
  int K, M, N;
  float alpha, beta;
  long sA, sB, sO, sD;
  void *o0,*o1,*o2,*o3,*o4;
  const void *e0,*e1;
  long ldo0, ldo1, ldE;
};

enum { E_F32=0, E_BF16=1, E_BF16T2=2, E_SPLIT=3, E_QW=4, E_PRE=5, E_GH=6, E_OUT=7 };

template<int BM, int BN, int EPI, bool SPLIT, bool TRX>
__global__ __launch_bounds__(256) void gemm_k(GA gq, GA gr, int zsplit)
{
  // ---- shared memory: NBUF staging buffers, tb aliased on top ------------
  constexpr int AH = BM*32;                        // ush per A panel
  constexpr int BH = BN*32;                        // ush per B panel
  constexpr int PANEL = (AH+BH) * (SPLIT ? 2 : 1); // one buffer (ush)
  constexpr int DEPTH = (PANEL <= 4096) ? 2 : 1;   // prefetch depth
  constexpr int NBUF  = DEPTH + 2;
  constexpr int TBN = TRX ? 64*65*2 : 0;           // tb as ush count
  constexpr int SMN = (NBUF*PANEL > TBN) ? NBUF*PANEL : TBN;
  __shared__ ush smem[SMN] __attribute__((aligned(16)));
  uint32* tb = (uint32*)smem;                      // valid only after k-loop

  // loads issued per thread per STAGE (compile-time)
  constexpr int LPS = (BM/64 + BN/64) * (SPLIT ? 2 : 1);

  GA g; int bz;
  if ((int)blockIdx.z < zsplit){ g = gq; bz = blockIdx.z; }
  else                         { g = gr; bz = blockIdx.z - zsplit; }

  // supertile swizzle: groups of 8 block-rows, column-major inside a group
  const int gx = gridDim.x, gy = gridDim.y;
  const int lin = blockIdx.y*gx + blockIdx.x;
  const int per = gx*8;
  const int grp = lin / per;
  const int rem = lin - grp*per;
  int gh = gy - grp*8; if (gh > 8) gh = 8;
  const int by = grp*8 + rem % gh;
  const int bx = rem / gh;
  const int m0 = by * BM;
  const int n0 = bx * BN;
  if (m0 >= g.M || n0 >= g.N) return;

  const int t = threadIdx.x;
  const int lane = t & 63;
  const int wave = t >> 6;
  const int wm = (wave >> 1) * (BM/2);
  const int wn = (wave & 1) * (BN/2);
  constexpr int MT = BM/32;
  constexpr int NT = BN/32;

  const ush* Ah  = g.A0h + (long)bz*g.sA;
  const ush* Alp = SPLIT ? g.A0l + (long)bz*g.sA : nullptr;
  const ush* Bhp = g.Bh  + (long)bz*g.sB;
  const ush* Blp = SPLIT ? g.Bl  + (long)bz*g.sB : nullptr;

  f4v acc[MT][NT];
  #pragma unroll
  for (int i=0;i<MT;i++)
    #pragma unroll
    for (int j=0;j<NT;j++) acc[i][j] = f4v{0.f,0.f,0.f,0.f};

  const int sr  = lane >> 2;
  const int scg = lane & 3;

  // stage one 32-K tile into buffer nb (0..NBUF-1)
  auto STAGE = [&](int k0, int nb){
    ush* dA  = smem + nb*PANEL;
    ush* dB  = dA + AH;
    ush* dAl = dB + BH;
    ush* dBl = dAl + AH;
    #pragma unroll
    for (int p = 0; p < BM/64; ++p) {
      const int lr = wave*16 + sr + p*64;
      const int gc = scg ^ ((lr>>1)&3);
      const int kc = k0 + gc*8;
      long aoff; const ush* gp;
      if (kc < g.ksplit){ aoff = (long)(m0+lr)*g.lda0 + kc;               gp = Ah + aoff; }
      else              { aoff = (long)(m0+lr)*g.lda1 + (kc - g.ksplit);  gp = g.A1h + aoff; }
      gload16(gp, &dA[(wave*16 + p*64)*32]);
      if (SPLIT) gload16(Alp + aoff, &dAl[(wave*16 + p*64)*32]);
    }
    #pragma unroll
    for (int p = 0; p < BN/64; ++p) {
      const int lr = wave*16 + sr + p*64;
      const int gc = scg ^ ((lr>>1)&3);
      const long boff = (long)(n0+lr)*g.ldb + k0 + gc*8;
      gload16(Bhp + boff, &dB[(wave*16 + p*64)*32]);
      if (SPLIT) gload16(Blp + boff, &dBl[(wave*16 + p*64)*32]);
    }
  };

  // ---- K-loop: depth-DEPTH prefetch, counted vmcnt, ONE s_barrier/step ----
  STAGE(0, 0);
  if (DEPTH == 2 && g.K > 32) STAGE(32, 1);
  int cur = 0;
  for (int k0 = 0; k0 < g.K; k0 += 32) {
    const int rem_steps = ((g.K - k0) >> 5) - 1;   // steps after current
    if (DEPTH == 2) {
      if (rem_steps >= 2) {
        const int nb = (cur+2 >= NBUF) ? cur+2-NBUF : cur+2;
        STAGE(k0 + 64, nb);
        asm volatile("s_waitcnt vmcnt(%0)" :: "n"(2*LPS) : "memory");
      } else if (rem_steps == 1) {
        asm volatile("s_waitcnt vmcnt(%0)" :: "n"(LPS) : "memory");
      } else {
        asm volatile("s_waitcnt vmcnt(0)" ::: "memory");
      }
    } else {
      if (rem_steps >= 1) {
        const int nb = (cur+1 >= NBUF) ? cur+1-NBUF : cur+1;
        STAGE(k0 + 32, nb);
        asm volatile("s_waitcnt vmcnt(%0)" :: "n"(LPS) : "memory");
      } else {
        asm volatile("s_waitcnt vmcnt(0)" ::: "memory");
      }
    }
    __builtin_amdgcn_sched_barrier(0);
    __builtin_amdgcn_s_barrier();      // all waves have buf(cur) resident
    __builtin_amdgcn_sched_barrier(0);

    const ush* rA  = smem + cur*PANEL;
    const ush* rB  = rA + AH;
    const ush* rAl = rB + BH;
    const ush* rBl = rAl + AH;

    const int fr = lane & 15;
    const int cc = lane >> 4;
    s8v af[MT], bf_[NT];
    #pragma unroll
    for (int i=0;i<MT;i++){ const int row = wm + i*16 + fr;
      af[i] = *(const s8v*)(&rA[row*32 + ((cc ^ ((row>>1)&3))<<3)]); }
    #pragma unroll
    for (int j=0;j<NT;j++){ const int row = wn + j*16 + fr;
      bf_[j] = *(const s8v*)(&rB[row*32 + ((cc ^ ((row>>1)&3))<<3)]); }
    #pragma unroll
    for (int i=0;i<MT;i++)
      #pragma unroll
      for (int j=0;j<NT;j++)
        acc[i][j] = __builtin_amdgcn_mfma_f32_16x16x32_bf16(af[i], bf_[j], acc[i][j], 0,0,0);
    if (SPLIT) {
      s8v al2[MT], bl2[NT];
      #pragma unroll
      for (int j=0;j<NT;j++){ const int row = wn + j*16 + fr;
        bl2[j] = *(const s8v*)(&rBl[row*32 + ((cc ^ ((row>>1)&3))<<3)]); }
      #pragma unroll
      for (int i=0;i<MT;i++){ const int row = wm + i*16 + fr;
        al2[i] = *(const s8v*)(&rAl[row*32 + ((cc ^ ((row>>1)&3))<<3)]); }
      #pragma unroll
      for (int i=0;i<MT;i++)
        #pragma unroll
        for (int j=0;j<NT;j++)
          acc[i][j] = __builtin_amdgcn_mfma_f32_16x16x32_bf16(af[i], bl2[j], acc[i][j], 0,0,0);
      #pragma unroll
      for (int i=0;i<MT;i++)
        #pragma unroll
        for (int j=0;j<NT;j++)
          acc[i][j] = __builtin_amdgcn_mfma_f32_16x16x32_bf16(al2[i], bf_[j], acc[i][j], 0,0,0);
    }
    cur = (cur+1 >= NBUF) ? 0 : cur+1;
  }

  // before epilogue: TRX writes tb over the staging alias -> need all waves
  // past their final MFMA reads of smem.
  if constexpr (TRX) __syncthreads();

  // ---------------- epilogue: direct writes (+ LDS staging for TRX) --------
  #pragma unroll
  for (int i=0;i<MT;i++)
    #pragma unroll
    for (int j=0;j<NT;j++)
      #pragma unroll
      for (int r=0;r<4;r++) {
        const int lrow = wm + i*16 + ((lane>>4)<<2) + r;
        const int lcol = wn + j*16 + (lane & 15);
        const int grow = m0 + lrow;
        const int gcol = n0 + lcol;
        float v = g.alpha * acc[i][j][r];
        if constexpr (EPI == E_F32) {
          if (g.e0) v += g.beta * ((const float*)g.e0)[(long)bz*g.sD + (long)grow*g.ldo0 + gcol];
          ((float*)g.o0)[(long)bz*g.sO + (long)grow*g.ldo0 + gcol] = v;
        } else if constexpr (EPI == E_BF16) {
          if (g.e0) v += g.beta * b2f(((const ush*)g.e0)[(long)bz*g.sD + (long)grow*g.ldo0 + gcol]);
          ((ush*)g.o0)[(long)bz*g.sO + (long)grow*g.ldo0 + gcol] = f2b(v);
        } else if constexpr (EPI == E_BF16T2) {
          if (g.e0) v += g.beta * b2f(((const ush*)g.e0)[(long)bz*g.sD + (long)grow*g.ldo0 + gcol]);
          ush hv = f2b(v);
          ((ush*)g.o0)[(long)bz*g.sO + (long)grow*g.ldo0 + gcol] = hv;
          tb[lrow*65 + lcol] = hv;
        } else if constexpr (EPI == E_SPLIT) {
          if (g.e0) v += g.beta * ((const float*)g.e0)[(long)bz*g.sD + (long)grow*g.ldo0 + gcol];
          if (g.o0) ((float*)g.o0)[(long)bz*g.sO + (long)grow*g.ldo0 + gcol] = v;
          ush hv = f2b(v);
          ush lv = f2b(v - b2f(hv));
          ((ush*)g.o1)[(long)bz*g.sO + (long)grow*g.ldo0 + gcol] = hv;
          ((ush*)g.o2)[(long)bz*g.sO + (long)grow*g.ldo0 + gcol] = lv;
          if (TRX) tb[lrow*65 + lcol] = (uint32)hv | ((uint32)lv<<16);
        } else if constexpr (EPI == E_QW) {
          ush hv = f2b(v);
          ((ush*)g.o0)[(long)bz*g.sO + (long)grow*g.ldo0 + gcol] = hv;
          tb[lrow*65 + lcol] = hv;
        } else if constexpr (EPI == E_PRE) {
          v += ((const float*)g.e0)[gcol];
          v = v > 0.f ? v : 0.f;
          ((ush*)g.o0)[(long)grow*g.ldo0 + gcol] = f2b(v);
        } else if constexpr (EPI == E_GH) {
          if (gcol < 512) {
            float h = v - b2f(((const ush*)g.e0)[(long)grow*g.ldE + gcol]);
            ush hb = f2b(h);
            ((ush*)g.o0)[(long)grow*512 + gcol] = hb;
            if (g.o2) ((ush*)g.o2)[(long)grow*4096 + gcol] = hb;
          } else {
            float y = b2f(((const ush*)g.e1)[(long)grow*512 + (gcol-512)]) - v;
            ((ush*)g.o1)[(long)grow*4096 + (gcol-512)] = f2b(y);
          }
        } else if constexpr (EPI == E_OUT) {
          float o = 0.5f*(10.1f*((const float*)g.e0)[(long)grow*1024 + gcol] + v)
                  + ((const float*)g.e1)[gcol];
          ((float*)g.o0)[(long)grow*1024 + gcol] = o;
        }
      }

  // ---------------- transposed writes (coalesced via LDS) ------------------
  if constexpr (TRX) {
    __syncthreads();
    const int tr  = t >> 2;     // transposed row = original col
    const int seg = t & 3;
    uint32 vals[16];
    #pragma unroll
    for (int u=0;u<16;u++) vals[u] = tb[(seg*16+u)*65 + tr];
    ush hb[16] __attribute__((aligned(16)));
    ush lb[16] __attribute__((aligned(16)));
    #pragma unroll
    for (int u=0;u<16;u++){ hb[u] = (ush)(vals[u]&0xffffu); lb[u] = (ush)(vals[u]>>16); }
    const long bT = (long)bz*g.sO + (long)(n0+tr)*g.ldo1 + m0 + seg*16;
    if constexpr (EPI == E_BF16T2) {
      st16((ush*)g.o1 + bT, hb);
    } else if constexpr (EPI == E_SPLIT) {
      if (g.o3) { st16((ush*)g.o3 + bT, hb); st16((ush*)g.o4 + bT, lb); }
    } else if constexpr (EPI == E_QW) {
      st16((ush*)g.o1 + bT, hb);
    }
  }
}

// ---------------- fused phase-4 NS building blocks -------------------------
// One 64-col GEMM tile job: MT=1 -> 32x64 (Q-half, K=1024), MT=2 -> 64x64
// (R, K=512).  4 LDS buffers of 8KB, depth-2 counted-vmcnt pipeline.
template<int MT>
DEV void ns_gemm(ush* smem, int m0, int n0, int ld, int K,
                 const ush* __restrict__ A, const ush* __restrict__ B,
                 bool g2, const ush* __restrict__ e0, ush* o0, ush* oT,
                 int t, int lane, int wave)
{
  uint32* tb = (uint32*)smem;
  const int wm = (wave>>1)*(MT*16), wn = (wave&1)*32;
  const int sr = lane>>2, scg = lane&3;
  const int fr = lane&15, cc = lane>>4;

  f4v acc[MT][2];
  #pragma unroll
  for (int i=0;i<MT;i++)
    #pragma unroll
    for (int j=0;j<2;j++) acc[i][j] = f4v{0.f,0.f,0.f,0.f};

  auto STAGE = [&](int k0, int nb){
    ush* dA = smem + nb*4096;
    ush* dB = dA + 2048;
    const int lr = wave*16 + sr;
    const int gc = scg ^ ((lr>>1)&3);
    if (MT==2 || lr < 32)
      gload16(A + (long)(m0+lr)*ld + k0 + gc*8, &dA[lr*32]);
    gload16(B + (long)(n0+lr)*ld + k0 + gc*8, &dB[lr*32]);
  };
  STAGE(0,0); STAGE(32,1);
  int cur = 0;
  for (int k0 = 0; k0 < K; k0 += 32){
    const int rem = ((K - k0) >> 5) - 1;
    if (rem >= 2){
      STAGE(k0+64, (cur+2)&3);
      if (MT==2 || wave < 2) asm volatile("s_waitcnt vmcnt(4)" ::: "memory");
      else                   asm volatile("s_waitcnt vmcnt(2)" ::: "memory");
    } else if (rem == 1){
      if (MT==2 || wave < 2) asm volatile("s_waitcnt vmcnt(2)" ::: "memory");
      else                   asm volatile("s_waitcnt vmcnt(1)" ::: "memory");
    } else {
      asm volatile("s_waitcnt vmcnt(0)" ::: "memory");
    }
    __builtin_amdgcn_sched_barrier(0);
    __builtin_amdgcn_s_barrier();
    __builtin_amdgcn_sched_barrier(0);
    const ush* rA = smem + cur*4096;
    const ush* rB = rA + 2048;
    s8v af[MT], bf_[2];
    #pragma unroll
    for (int i=0;i<MT;i++){ const int row = wm+i*16+fr;
      af[i] = *(const s8v*)&rA[row*32 + ((cc ^ ((row>>1)&3))<<3)]; }
    #pragma unroll
    for (int j=0;j<2;j++){ const int row = wn+j*16+fr;
      bf_[j] = *(const s8v*)&rB[row*32 + ((cc ^ ((row>>1)&3))<<3)]; }
    #pragma unroll
    for (int i=0;i<MT;i++)
      #pragma unroll
      for (int j=0;j<2;j++)
        acc[i][j] = __builtin_amdgcn_mfma_f32_16x16x32_bf16(af[i],bf_[j],acc[i][j],0,0,0);
    cur = (cur+1)&3;
  }

  if (g2) __syncthreads();   // tb aliases staging bufs
  #pragma unroll
  for (int i=0;i<MT;i++)
    #pragma unroll
    for (int j=0;j<2;j++)
      #pragma unroll
      for (int r=0;r<4;r++){
        const int lrow = wm + i*16 + ((lane>>4)<<2) + r;
        const int lcol = wn + j*16 + fr;
        const long off = (long)(m0+lrow)*ld + n0 + lcol;
        if (!g2){
          o0[off] = f2b(acc[i][j][r]);
        } else {
          float v = 2.f*b2f(e0[off]) - acc[i][j][r];
          ush hv = f2b(v);
          o0[off] = hv;
          tb[lrow*65 + lcol] = hv;
        }
      }
  if (g2){
    __syncthreads();
    const int tr = t>>2, seg = t&3;
    if (seg < 2*MT){
      uint32 vals[16];
      #pragma unroll
      for (int u=0;u<16;u++) vals[u] = tb[(seg*16+u)*65 + tr];
      ush hb[16] __attribute__((aligned(16)));
      #pragma unroll
      for (int u=0;u<16;u++) hb[u] = (ush)vals[u];
      st16(oT + (long)(n0+tr)*ld + m0 + seg*16, hb);
    }
  }
}

// 9 iterations of { Yh = (M X)^T ; X' = 2X - X Y^T } on Q (1024^2) + 8 R
// (512^2).  1024 balanced jobs, job-strided over gridDim.x blocks (grid set
// by host occupancy query -> co-residency guaranteed).  Monotone tree
// grid-barrier (no resets, spread spin addresses), ngroups = grid/32.
__global__ __launch_bounds__(256) void ns_fused(
    const ush* __restrict__ Mh, ush* XhA, ush* XThA, ush* XhB, ush* XThB,
    ush* Yh, uint32* bar, int iters)
{
  __shared__ ush smem[4*4096] __attribute__((aligned(16)));   // 32 KB

  const int b = blockIdx.x;
  const int grid = gridDim.x;
  const uint32 ngroups = (uint32)(grid >> 5);
  const int t = threadIdx.x, lane = t&63, wave = t>>6;

  auto decode = [&](int j, int& m0, int& n0, int& ld, int& K, int& mt, long& base){
    if (j < 512){            // Q-half job: 32x64 tile, K=1024
      const int tile = j>>1, half = j&1;
      m0 = (tile>>4)*64 + half*32; n0 = (tile&15)*64;
      base = 0; ld = 1024; K = 1024; mt = 1;
    } else {                 // R job: 64x64 tile, K=512
      const int rj = j - 512;
      const int z = rj>>6, idx = rj&63;
      m0 = (idx>>3)<<6; n0 = (idx&7)<<6;
      base = 1048576l + (long)z*262144l; ld = 512; K = 512; mt = 2;
    }
  };

  // bar layout (uint32 idx): arrival g*32 (g<32), go 1024+g*32, root 2048,
  // gen 2080.  All counters monotone -- no resets.
  int barno = 0;
  auto gbar = [&](){
    __syncthreads();
    if (t == 0){
      __threadfence();
      const int grp = b >> 5;
      const uint32 tgt = 32u*(uint32)(barno+1);
      __hip_atomic_fetch_add(&bar[grp*32], 1u,
            __ATOMIC_RELEASE, __HIP_MEMORY_SCOPE_AGENT);
      if ((b & 31) == 0){                     // group leader
        while (__hip_atomic_load(&bar[grp*32],
              __ATOMIC_ACQUIRE, __HIP_MEMORY_SCOPE_AGENT) < tgt)
          __builtin_amdgcn_s_sleep(8);
        __hip_atomic_fetch_add(&bar[2048], 1u,
              __ATOMIC_ACQ_REL, __HIP_MEMORY_SCOPE_AGENT);
        if (b == 0){                          // root
          const uint32 rtgt = ngroups*(uint32)(barno+1);
          while (__hip_atomic_load(&bar[2048],
                __ATOMIC_ACQUIRE, __HIP_MEMORY_SCOPE_AGENT) < rtgt)
            __builtin_amdgcn_s_sleep(8);
          __hip_atomic_store(&bar[2080], (uint32)(barno+1),
                __ATOMIC_RELEASE, __HIP_MEMORY_SCOPE_AGENT);
        }
        while (__hip_atomic_load(&bar[2080],
              __ATOMIC_ACQUIRE, __HIP_MEMORY_SCOPE_AGENT) < (uint32)(barno+1))
          __builtin_amdgcn_s_sleep(8);
        __hip_atomic_store(&bar[1024 + grp*32], (uint32)(barno+1),
              __ATOMIC_RELEASE, __HIP_MEMORY_SCOPE_AGENT);
      } else {
        while (__hip_atomic_load(&bar[1024 + grp*32],
              __ATOMIC_ACQUIRE, __HIP_MEMORY_SCOPE_AGENT) < (uint32)(barno+1))
          __builtin_amdgcn_s_sleep(8);
      }
      __threadfence();
    }
    __syncthreads();
    ++barno;
  };

  ush* X[2]  = {XhA, XhB};
  ush* XT[2] = {XThA, XThB};
  int cur = 0;
  for (int it = 0; it < iters; ++it){
    // GEMM1: Yh = (M X)^T  == XT[cur] * Mh^T   (all jobs, strided)
    for (int j = b; j < 1024; j += grid){
      int m0,n0,ld,K,mt; long base;
      decode(j, m0,n0,ld,K,mt,base);
      if (mt == 1) ns_gemm<1>(smem, m0, n0, ld, K, XT[cur]+base, Mh+base,
                              false, nullptr, Yh+base, nullptr, t, lane, wave);
      else         ns_gemm<2>(smem, m0, n0, ld, K, XT[cur]+base, Mh+base,
                              false, nullptr, Yh+base, nullptr, t, lane, wave);
      __syncthreads();       // LDS buffer reuse across jobs (drains vm/lgkm)
    }
    gbar();
    // GEMM2: X[nxt] = 2 X[cur] - X[cur] * Yh^T  (+ transposed copy)
    for (int j = b; j < 1024; j += grid){
      int m0,n0,ld,K,mt; long base;
      decode(j, m0,n0,ld,K,mt,base);
      if (mt == 1) ns_gemm<1>(smem, m0, n0, ld, K, X[cur]+base, Yh+base,
                              true, X[cur]+base, X[cur^1]+base, XT[cur^1]+base,
                              t, lane, wave);
      else         ns_gemm<2>(smem, m0, n0, ld, K, X[cur]+base, Yh+base,
                              true, X[cur]+base, X[cur^1]+base, XT[cur^1]+base,
                              t, lane, wave);
      __syncthreads();
    }
    if (it != iters-1) gbar();
    cur ^= 1;
  }
}

// ------------------------------ small kernels ------------------------------

__global__ __launch_bounds__(256) void k_norms(const float* __restrict__ Fq,
    const float* __restrict__ Fr0, const float* __restrict__ Frr, float* s2){
  const int y = blockIdx.y;
  const float* p; long cnt4;
  if (y==0){ p=Fq; cnt4=1048576l; }
  else if (y==1){ p=Fr0; cnt4=65536l; }
  else { p=Frr + (long)(y-2)*524288; cnt4=131072l; }
  float s = 0.f;
  for (long i = (long)blockIdx.x*256 + threadIdx.x; i < cnt4; i += (long)gridDim.x*256){
    float4 v = ((const float4*)p)[i];
    s += v.x*v.x + v.y*v.y + v.z*v.z + v.w*v.w;
  }
  #pragma unroll
  for (int o=32;o>0;o>>=1) s += __shfl_down(s, o, 64);
  __shared__ float red[4];
  if ((threadIdx.x & 63)==0) red[threadIdx.x>>6] = s;
  __syncthreads();
  if (threadIdx.x==0) atomicAdd(&s2[y], red[0]+red[1]+red[2]+red[3]);
}

__global__ void k_scales(const float* s2, const float* fq, const float* fr, float* sc){
  int t = threadIdx.x;
  if (t < 9){
    float v = (t==0)? fq[0] : fr[t-1];
    sc[t] = v / (sqrtf(s2[t]) + 1e-5f);
  }
}

// tiled build of V (3072x1024, z=0) and Wr (7x512x512, z=1..7), hi/lo + transpose
__global__ __launch_bounds__(256) void k_buildT(const float* __restrict__ Fq,
    const float* __restrict__ Frr, const float* sc,
    ush* Vh, ush* Vl, ush* Vth, ush* Vtl,
    ush* Wrh, ush* Wrl, ush* WrTh, ush* WrTl){
  __shared__ uint32 tb[64*65];
  const int z = blockIdx.z;
  const int r = threadIdx.x >> 2;
  const int cs = (threadIdx.x & 3)*16;
  ush hh[16] __attribute__((aligned(16)));
  ush ll[16] __attribute__((aligned(16)));
  if (z==0){
    const long r0 = (long)blockIdx.y*64, c0 = (long)blockIdx.x*64;
    const float s = sc[0];
    const float* src = &Fq[(1024+r0+r)*1024 + c0 + cs];
    #pragma unroll
    for (int u=0;u<16;u++){
      float v = s*src[u];
      ush h = f2b(v); ush l = f2b(v - b2f(h));
      hh[u]=h; ll[u]=l;
      tb[r*65 + cs + u] = (uint32)h | ((uint32)l<<16);
    }
    st16(&Vh[(r0+r)*1024 + c0 + cs], hh);
    st16(&Vl[(r0+r)*1024 + c0 + cs], ll);
    __syncthreads();
    const int tr = threadIdx.x>>2, seg = threadIdx.x&3;
    #pragma unroll
    for (int u=0;u<16;u++){
      uint32 v = tb[(seg*16+u)*65 + tr];
      hh[u]=(ush)(v&0xffffu); ll[u]=(ush)(v>>16);
    }
    st16(&Vth[(c0+tr)*3072 + r0 + seg*16], hh);
    st16(&Vtl[(c0+tr)*3072 + r0 + seg*16], ll);
  } else {
    if (blockIdx.x>=8 || blockIdx.y>=8) return;
    const int k = z-1;
    const long r0 = (long)blockIdx.y*64, c0 = (long)blockIdx.x*64;
    const float s = sc[2+k];
    const float* src = &Frr[(long)k*524288 + (r0+r)*1024 + 512 + c0 + cs];
    #pragma unroll
    for (int u=0;u<16;u++){
      float v = s*src[u];
      ush h = f2b(v); ush l = f2b(v - b2f(h));
      hh[u]=h; ll[u]=l;
      tb[r*65 + cs + u] = (uint32)h | ((uint32)l<<16);
    }
    st16(&Wrh[(long)k*262144 + (r0+r)*512 + c0 + cs], hh);
    st16(&Wrl[(long)k*262144 + (r0+r)*512 + c0 + cs], ll);
    __syncthreads();
    const int tr = threadIdx.x>>2, seg = threadIdx.x&3;
    #pragma unroll
    for (int u=0;u<16;u++){
      uint32 v = tb[(seg*16+u)*65 + tr];
      hh[u]=(ush)(v&0xffffu); ll[u]=(ush)(v>>16);
    }
    st16(&WrTh[(long)k*262144 + (c0+tr)*512 + r0 + seg*16], hh);
    st16(&WrTl[(long)k*262144 + (c0+tr)*512 + r0 + seg*16], ll);
  }
}

// tiled assembly of M = I + A (hi/lo) and M^T: z=0 Q (16x16 tiles), z=1..8 R (8x8)
__global__ __launch_bounds__(256) void k_asmT(const float* __restrict__ Fq,
    const float* __restrict__ Fr0, const float* __restrict__ Frr,
    const float* sc, const float* __restrict__ PP,
    ush* Mh, ush* Ml, ush* MTh, ush* MTl){
  __shared__ uint32 tb[64*65];
  const int z = blockIdx.z;
  const int r = threadIdx.x >> 2;
  const int cs = (threadIdx.x & 3)*16;
  const long ROFF = 1048576l, RS = 262144l;
  long r0 = (long)blockIdx.y*64, c0 = (long)blockIdx.x*64;
  const float* dsrc; const float* msrc; const float* psrc = nullptr;
  float s; long obase; long old_; float sgn;
  if (z==0){
    s = sc[0]; sgn = 1.f;
    dsrc = &Fq[(r0+r)*1024 + c0 + cs];
    msrc = &Fq[(c0+r)*1024 + r0 + cs];
    psrc = &PP[(r0+r)*1024 + c0 + cs];
    obase = 0; old_ = 1024;
  } else {
    if (blockIdx.x>=8 || blockIdx.y>=8) return;
    const int b = z-1;
    if (b==0){
      s = sc[1]; sgn = 1.f;
      dsrc = &Fr0[(r0+r)*512 + c0 + cs];
      msrc = &Fr0[(c0+r)*512 + r0 + cs];
    } else {
      s = sc[1+b]; sgn = -1.f;   // a = s*(W[c][r]-W[r][c]) = s*(mirror-direct)
      const float* W = Frr + (long)(b-1)*524288;
      dsrc = &W[(r0+r)*1024 + c0 + cs];
      msrc = &W[(c0+r)*1024 + r0 + cs];
      psrc = &PP[ROFF + (long)(b-1)*RS + (r0+r)*512 + c0 + cs];
    }
    obase = ROFF + (long)b*RS; old_ = 512;
  }
  // stage mirror tile (float bits)
  #pragma unroll
  for (int u=0;u<16;u++) tb[r*65 + cs + u] = __float_as_uint(msrc[u]);
  __syncthreads();
  ush hh[16] __attribute__((aligned(16)));
  ush ll[16] __attribute__((aligned(16)));
  #pragma unroll
  for (int u=0;u<16;u++){
    const int c = cs + u;
    float mir = __uint_as_float(tb[c*65 + r]);
    float a = sgn * s * (dsrc[u] - mir);
    if (psrc) a += psrc[u];
    float m = ((r0 + r == c0 + c) ? 1.f : 0.f) + a;
    ush h = f2b(m); ush l = f2b(m - b2f(h));
    hh[u]=h; ll[u]=l;
  }
  st16(&Mh[obase + (r0+r)*old_ + c0 + cs], hh);
  st16(&Ml[obase + (r0+r)*old_ + c0 + cs], ll);
  __syncthreads();
  #pragma unroll
  for (int u=0;u<16;u++) tb[r*65 + cs + u] = (uint32)hh[u] | ((uint32)ll[u]<<16);
  __syncthreads();
  const int tr = threadIdx.x>>2, seg = threadIdx.x&3;
  #pragma unroll
  for (int u=0;u<16;u++){
    uint32 v = tb[(seg*16+u)*65 + tr];
    hh[u]=(ush)(v&0xffffu); ll[u]=(ush)(v>>16);
  }
  st16(&MTh[obase + (c0+tr)*old_ + r0 + seg*16], hh);
  st16(&MTl[obase + (c0+tr)*old_ + r0 + seg*16], ll);
}

__global__ __launch_bounds__(256) void k_rowabs(const float* __restrict__ T2, float* bmax){
  const int y = blockIdx.y;
  const float* row; int n;
  if (y==0){ row = T2 + (long)blockIdx.x*1024; n = 1024; }
  else { if (blockIdx.x >= 512) return;
         row = T2 + 1048576l + (long)(y-1)*262144 + (long)blockIdx.x*512; n = 512; }
  float s=0.f;
  for (int i=threadIdx.x;i<n;i+=256) s += fabsf(row[i]);
  #pragma unroll
  for (int o=32;o>0;o>>=1) s += __shfl_down(s,o,64);
  __shared__ float red[4];
  if ((threadIdx.x&63)==0) red[threadIdx.x>>6]=s;
  __syncthreads();
  if (threadIdx.x==0){
    float tot = red[0]+red[1]+red[2]+red[3];
    atomicMax((unsigned int*)&bmax[y], __float_as_uint(tot));
  }
}

__global__ void k_makec(const float* bmax, float* cvl){
  int t=threadIdx.x;
  if (t<9){
    float bnd = sqrtf(fmaxf(bmax[t], 1.f));   // >= sigma_max(M)^2
    cvl[t] = 1.9f/(1.f + bnd);
  }
}

__global__ __launch_bounds__(256) void k_initX(const ush* __restrict__ Mh,
    const ush* __restrict__ MTh, const float* cvl, ush* Xh, ush* XTh){
  long i = (long)blockIdx.x*256 + threadIdx.x;
  int b = (i < 1048576l) ? 0 : 1 + (int)((i - 1048576l) >> 18);
  float c = cvl[b];
  Xh[i]  = f2b(c * b2f(MTh[i]));
  XTh[i] = f2b(c * b2f(Mh[i]));
}

__global__ __launch_bounds__(256) void k_promote(const ush* __restrict__ Xh,
    float* Xf, ush* Xl, ush* XTl){
  long i = (long)blockIdx.x*256 + threadIdx.x;
  Xf[i] = b2f(Xh[i]);
  Xl[i] = 0; XTl[i] = 0;
}

// tops: 2X - I, tiled, value + transposed copy.  z=0 Q (16x16), z=1..8 R (8x8)
__global__ __launch_bounds__(256) void k_topT(const ush* __restrict__ Xh, const ush* __restrict__ Xl,
    ush* Qb, ush* QTb, ush* RK, ush* RKT){
  __shared__ uint32 tb[64*65];
  const int z = blockIdx.z;
  const int r = threadIdx.x >> 2;
  const int cs = (threadIdx.x & 3)*16;
  const long ROFF = 1048576l, RS = 262144l;
  long r0 = (long)blockIdx.y*64, c0 = (long)blockIdx.x*64;
  ush hh[16] __attribute__((aligned(16)));
  if (z==0){
    const long base = (r0+r)*1024 + c0 + cs;
    #pragma unroll
    for (int u=0;u<16;u++){
      float v = 2.f*(b2f(Xh[base+u]) + b2f(Xl[base+u])) - ((r0+r == c0+cs+u)?1.f:0.f);
      hh[u] = f2b(v);
      tb[r*65 + cs + u] = hh[u];
    }
    st16(&Qb[(r0+r)*1024 + c0 + cs], hh);
    __syncthreads();
    const int tr = threadIdx.x>>2, seg = threadIdx.x&3;
    #pragma unroll
    for (int u=0;u<16;u++) hh[u] = (ush)tb[(seg*16+u)*65 + tr];
    st16(&QTb[(c0+tr)*4096 + r0 + seg*16], hh);
  } else {
    if (blockIdx.x>=8 || blockIdx.y>=8) return;
    const int b = z-1;
    const long base = ROFF + (long)b*RS + (r0+r)*512 + c0 + cs;
    #pragma unroll
    for (int u=0;u<16;u++){
      float v = 2.f*(b2f(Xh[base+u]) + b2f(Xl[base+u])) - ((r0+r == c0+cs+u)?1.f:0.f);
      hh[u] = f2b(v);
      tb[r*65 + cs + u] = hh[u];
    }
    st16(&RKT[(long)b*524288 + (r0+r)*512 + c0 + cs], hh);
    __syncthreads();
    const int tr = threadIdx.x>>2, seg = threadIdx.x&3;
    #pragma unroll
    for (int u=0;u<16;u++) hh[u] = (ush)tb[(seg*16+u)*65 + tr];
    st16(&RK[(long)b*524288 + (c0+tr)*1024 + r0 + seg*16], hh);
  }
}

__global__ __launch_bounds__(256) void k_f2bf(const float* __restrict__ in, ush* __restrict__ o){
  long i = ((long)blockIdx.x*256 + threadIdx.x)*8;
  float4 a = *(const float4*)(in+i);
  float4 b = *(const float4*)(in+i+4);
  ush u[8] __attribute__((aligned(16)));
  u[0]=f2b(a.x);u[1]=f2b(a.y);u[2]=f2b(a.z);u[3]=f2b(a.w);
  u[4]=f2b(b.x);u[5]=f2b(b.y);u[6]=f2b(b.z);u[7]=f2b(b.w);
  *(int4*)(o+i) = *(const int4*)u;
}

// ------------------------------ host driver -------------------------------

static GA mk(const ush* Ah, const ush* Al, long lda,
             const ush* Bh, const ush* Bl, long ldb,
             int K, int M, int N, float alpha){
  GA g{}; g.ksplit=1<<30; g.A0h=Ah; g.A0l=Al; g.lda0=lda;
  g.Bh=Bh; g.Bl=Bl; g.ldb=ldb; g.K=K; g.M=M; g.N=N; g.alpha=alpha; g.beta=0.f;
  return g;
}

extern "C" void kernel_launch(void* const* d_in, const int* in_sizes, int n_in,
                              void* d_out, int out_size, void* d_ws, size_t ws_size,
                              hipStream_t stream)
{
  (void)in_sizes; (void)n_in; (void)out_size; (void)ws_size;
  const float* x   = (const float*)d_in[0];
  const float* Fq  = (const float*)d_in[1];
  const float* fqp = (const float*)d_in[2];
  const float* by  = (const float*)d_in[3];
  const float* Fr0 = (const float*)d_in[4];
  const float* Frr = (const float*)d_in[5];
  const float* frp = (const float*)d_in[6];
  const float* bp  = (const float*)d_in[7];
  float* out = (float*)d_out;

  const float SQG = sqrtf(10.0f - 0.1f);
  const float SQ2 = sqrtf(2.0f);
  const long UN = 3145728l;
  const long ROFF = 1048576l, RS = 262144l;

  char* base = (char*)d_ws;
  size_t off = 0;
  auto alloc = [&](size_t bytes)->char*{
    char* p = base + off; off = (off + bytes + 255) & ~(size_t)255; return p;
  };

  // ---- persistent ----
  ush* Qb  = (ush*)alloc(4194304l*2);
  ush* QTb = (ush*)alloc(4194304l*2);
  ush* RK  = (ush*)alloc(4194304l*2);
  ush* RKT = (ush*)alloc(4194304l*2);
  ush* xbf = (ush*)alloc(8388608l*2);
  float* scal = (float*)alloc(256*4);
  float* s2   = scal;
  float* bmax = scal + 16;
  float* cvl  = scal + 32;
  float* sc   = scal + 48;
  uint32* bar = (uint32*)alloc(16384);

  const size_t scratch0 = off;
  ush* Vh   = (ush*)alloc(UN*2);
  ush* Vl   = (ush*)alloc(UN*2);
  ush* Vth  = (ush*)alloc(UN*2);
  ush* Vtl  = (ush*)alloc(UN*2);
  ush* Wrh  = (ush*)alloc(1835008l*2);
  ush* Wrl  = (ush*)alloc(1835008l*2);
  ush* WrTh = (ush*)alloc(1835008l*2);
  ush* WrTl = (ush*)alloc(1835008l*2);
  float* PPf = (float*)alloc(UN*4);
  ush* Mh  = (ush*)alloc(UN*2);
  ush* Ml  = (ush*)alloc(UN*2);
  ush* MTh = (ush*)alloc(UN*2);
  ush* MTl = (ush*)alloc(UN*2);
  ush* Sh  = (ush*)alloc(UN*2);
  ush* XhA = (ush*)alloc(UN*2);
  ush* XhB = (ush*)alloc(UN*2);
  ush* XlA = (ush*)alloc(UN*2);
  ush* XlB = (ush*)alloc(UN*2);
  ush* XThA = (ush*)alloc(UN*2);
  ush* XThB = (ush*)alloc(UN*2);
  ush* XTlA = (ush*)alloc(UN*2);
  ush* XTlB = (ush*)alloc(UN*2);
  float* XfA = (float*)alloc(UN*4);
  float* XfB = (float*)alloc(UN*4);
  ush* Yh  = (ush*)alloc(UN*2);
  ush* Yl  = (ush*)alloc(UN*2);

  ush* Xh[2]  = {XhA, XhB};
  ush* Xl[2]  = {XlA, XlB};
  ush* XTh[2] = {XThA, XThB};
  ush* XTl[2] = {XTlA, XTlB};
  float* Xf[2] = {XfA, XfB};

  dim3 B256(256);
  GA ga{}, gr{};

  // ---- phase 0: norms & scales ----
  (void)hipMemsetAsync(scal, 0, 1024, stream);
  (void)hipMemsetAsync(bar, 0, 16384, stream);
  k_norms<<<dim3(256,9),B256,0,stream>>>(Fq, Fr0, Frr, s2);
  k_scales<<<1,16,0,stream>>>(s2, fqp, frp, sc);

  // ---- phase 1: build V / Wr (tiled, coalesced) ----
  k_buildT<<<dim3(16,48,8),B256,0,stream>>>(Fq, Frr, sc, Vh,Vl,Vth,Vtl, Wrh,Wrl,WrTh,WrTl);

  // PQ = V^T V ; PR_k = Wr Wr^T (split) -> PPf
  ga = mk(Vth,Vtl,3072, Vth,Vtl,3072, 3072,1024,1024, 1.f); ga.o0=PPf; ga.ldo0=1024;
  gr = mk(Wrh,Wrl,512, Wrh,Wrl,512, 512,512,512, 1.f);
  gr.sA=RS; gr.sB=RS; gr.o0=PPf+ROFF; gr.sO=RS; gr.ldo0=512;
  gemm_k<64,64,E_F32,true,false><<<dim3(16,16,8),B256,0,stream>>>(ga,gr,1);

  // ---- phase 2: assemble M, M^T (tiled) ----
  k_asmT<<<dim3(16,16,9),B256,0,stream>>>(Fq, Fr0, Frr, sc, PPf, Mh,Ml,MTh,MTl);

  // ---- phase 3: bound: S = M*M^T (bf16), S^2 (f32), rowabs, c, X0 ----
  ga = mk(Mh,nullptr,1024, Mh,nullptr,1024, 1024,1024,1024, 1.f); ga.o0=Sh; ga.ldo0=1024;
  gr = mk(Mh+ROFF,nullptr,512, Mh+ROFF,nullptr,512, 512,512,512, 1.f);
  gr.sA=RS; gr.sB=RS; gr.o0=Sh+ROFF; gr.sO=RS; gr.ldo0=512;
  gemm_k<64,64,E_BF16,false,false><<<dim3(16,16,9),B256,0,stream>>>(ga,gr,1);

  ga = mk(Sh,nullptr,1024, Sh,nullptr,1024, 1024,1024,1024, 1.f); ga.o0=PPf; ga.ldo0=1024;
  gr = mk(Sh+ROFF,nullptr,512, Sh+ROFF,nullptr,512, 512,512,512, 1.f);
  gr.sA=RS; gr.sB=RS; gr.o0=PPf+ROFF; gr.sO=RS; gr.ldo0=512;
  gemm_k<64,64,E_F32,false,false><<<dim3(16,16,9),B256,0,stream>>>(ga,gr,1);
  k_rowabs<<<dim3(1024,9),B256,0,stream>>>(PPf, bmax);
  k_makec<<<1,16,0,stream>>>(bmax, cvl);
  k_initX<<<12288,B256,0,stream>>>(Mh, MTh, cvl, Xh[0], XTh[0]);

  // ---- phase 4: coupled NS bf16 (9 iters) -- FUSED persistent kernel ----
  // Grid sized by occupancy query so all blocks are guaranteed co-resident
  // (spin grid-barrier deadlocks otherwise).  Fallback 768 = R10-proven.
  int maxb = 0;
  if (hipOccupancyMaxActiveBlocksPerMultiprocessor(&maxb, ns_fused, 256, 0)
        != hipSuccess || maxb < 1) maxb = 3;
  int nsgrid = maxb * 256; if (nsgrid > 1024) nsgrid = 1024;
  ns_fused<<<nsgrid,B256,0,stream>>>(Mh, XhA, XThA, XhB, XThB, Yh, bar, 9);
  int cur = 1;   // 9 iterations: final X in buffer B

  // ---- phase 5: promote + 2 split-precision NS iters ----
  k_promote<<<12288,B256,0,stream>>>(Xh[cur], Xf[cur], Xl[cur], XTl[cur]);
  for (int it=0; it<2; ++it){
    int nxt = cur^1;
    ga = mk(XTh[cur],XTl[cur],1024, Mh,Ml,1024, 1024,1024,1024, 1.f);
    ga.o1=Yh; ga.o2=Yl; ga.ldo0=1024;
    gr = mk(XTh[cur]+ROFF,XTl[cur]+ROFF,512, Mh+ROFF,Ml+ROFF,512, 512,512,512, 1.f);
    gr.sA=RS; gr.sB=RS; gr.o1=Yh+ROFF; gr.o2=Yl+ROFF; gr.sO=RS; gr.ldo0=512;
    gemm_k<64,64,E_SPLIT,true,false><<<dim3(16,16,9),B256,0,stream>>>(ga,gr,1);

    ga = mk(Xh[cur],Xl[cur],1024, Yh,Yl,1024, 1024,1024,1024, -1.f);
    ga.beta=2.f; ga.e0=Xf[cur];
    ga.o0=Xf[nxt]; ga.o1=Xh[nxt]; ga.o2=Xl[nxt]; ga.o3=XTh[nxt]; ga.o4=XTl[nxt];
    ga.ldo0=1024; ga.ldo1=1024;
    gr = mk(Xh[cur]+ROFF,Xl[cur]+ROFF,512, Yh+ROFF,Yl+ROFF,512, 512,512,512, -1.f);
    gr.beta=2.f; gr.e0=Xf[cur]+ROFF; gr.sD=RS;
    gr.sA=RS; gr.sB=RS; gr.sO=RS;
    gr.o0=Xf[nxt]+ROFF; gr.o1=Xh[nxt]+ROFF; gr.o2=Xl[nxt]+ROFF;
    gr.o3=XTh[nxt]+ROFF; gr.o4=XTl[nxt]+ROFF;
    gr.ldo0=512; gr.ldo1=512;
    gemm_k<64,64,E_SPLIT,true,true><<<dim3(16,16,9),B256,0,stream>>>(ga,gr,1);
    cur = nxt;
  }

  // ---- phase 6: tops = 2X - I (tiled) ; bottoms = -2*V*X (QW + LDS transpose) ----
  k_topT<<<dim3(16,16,9),B256,0,stream>>>(Xh[cur], Xl[cur], Qb, QTb, RK, RKT);

  ga = mk(Vh,Vl,1024, XTh[cur],XTl[cur],1024, 1024,3072,1024, -2.f);
  ga.o0=Qb + 1048576l; ga.ldo0=1024; ga.o1=QTb + 1024; ga.ldo1=4096;
  gr = mk(WrTh,WrTl,512, XTh[cur]+ROFF+RS, XTl[cur]+ROFF+RS, 512, 512,512,512, -2.f);
  gr.sA=RS; gr.sB=RS; gr.sO=524288;
  gr.o0=RKT + 524288 + 262144; gr.ldo0=512;
  gr.o1=RK + 524288 + 512; gr.ldo1=1024;
  gemm_k<64,64,E_QW,true,true><<<dim3(16,48,8),B256,0,stream>>>(ga,gr,1);

  // ---- main-path overlay buffers ----
  off = scratch0;
  ush* xh  = (ush*)alloc(33554432l*2);
  ush* yh  = (ush*)alloc(33554432l*2);
  ush* pre = (ush*)alloc(4194304l*2);
  ush* h0  = (ush*)alloc(4194304l*2);
  ush* h1  = (ush*)alloc(4194304l*2);

  // ---- phase 7: main chain ----
  k_f2bf<<<4096,B256,0,stream>>>(x, xbf);
  ga = mk(xbf,nullptr,1024, Qb,nullptr,1024, 1024,8192,4096, SQG);
  ga.o0=xh; ga.ldo0=4096;
  gemm_k<128,128,E_BF16,false,false><<<dim3(32,64,1),B256,0,stream>>>(ga,ga,1);

  for (int k=0;k<8;++k){
    ush* hprev = (k==0)? nullptr : (((k-1)&1) ? h1 : h0);
    ush* hnew  = (k&1) ? h1 : h0;
    GA gp_ = mk(xh + (long)k*512, nullptr, 4096,
                (k==0)? RKT : RK + (long)k*524288, nullptr, (k==0)?512:1024,
                (k==0)?512:1024, 8192, 512, SQ2);
    gp_.ksplit = 512; gp_.A1h = hprev; gp_.lda1 = 512;
    gp_.e0 = bp + (long)k*512; gp_.o0 = pre; gp_.ldo0 = 512;
    gemm_k<128,64,E_PRE,false,false><<<dim3(8,64,1),B256,0,stream>>>(gp_,gp_,1);

    GA gg = mk(pre, nullptr, 512,
               (k==0)? RK : RKT + (long)k*524288, nullptr, (k==0)?1024:512,
               512, 8192, (k==0)?512:1024, SQ2);
    gg.e0 = xh + (long)k*512; gg.ldE = 4096;
    gg.e1 = hprev;
    gg.o0 = hnew;
    gg.o1 = (k>=1)? (void*)(yh + (long)(k-1)*512) : nullptr;
    gg.o2 = (k==7)? (void*)(yh + 3584) : nullptr;
    if (k==0) gemm_k<128,64,E_GH,false,false><<<dim3(8,64,1),B256,0,stream>>>(gg,gg,1);
    else      gemm_k<128,128,E_GH,false,false><<<dim3(8,64,1),B256,0,stream>>>(gg,gg,1);
  }

  // out = 0.5*(10.1*x + sqrt_gam*(yh@Q)) + by
  ga = mk(yh,nullptr,4096, QTb,nullptr,4096, 4096,8192,1024, SQG);
  ga.e0=x; ga.e1=by; ga.o0=out; ga.ldo0=1024;
  gemm_k<128,128,E_OUT,false,false><<<dim3(8,64,1),B256,0,stream>>>(ga,ga,1);
}

// Round 9
// 1387.886 us; speedup vs baseline: 2.3000x; 1.4915x over previous
//
#include <hip/hip_runtime.h>
#include <math.h>

// ---------------------------------------------------------------------------
// MonLipLayer forward on MI355X.  R13: persistent-kernel NS fusion ABANDONED
// (pre-committed decision): two barrier designs (R10 flat, R12 tree) both
// cost ~150us/grid-barrier on MI355X (AGENT-scope atomics across 8 non-
// coherent L2s + sleep/wake), unamortizable vs ~5us of work per phase.
// Phase 4 reverts to the proven 18-dispatch loop.
// KEPT: R7 counted-vmcnt multi-buffer pipelined K-loop (never drain vmcnt
// mid-loop); R8 vectorized k_norms (float4, full-chip grid); R12 depth-2
// prefetch threshold PANEL<=8KB (excludes E_PRE -> no 48KB-LDS occupancy
// regression).  R4: LDS-staged transposed writes; supertile swizzle.
// Math unchanged.  C = alpha * A(MxK,row) * Bt(NxK,row)^T + beta * D.
// ---------------------------------------------------------------------------

using s8v = __attribute__((ext_vector_type(8))) short;   // 8 x bf16
using f4v = __attribute__((ext_vector_type(4))) float;
typedef unsigned short ush;
typedef unsigned int uint32;

#define DEV __device__ __forceinline__

DEV float b2f(ush u){ union{unsigned int i; float f;} v; v.i = ((unsigned int)u)<<16; return v.f; }
DEV ush f2b(float f){
  union{float f; unsigned int i;} v; v.f = f;
  unsigned int u = v.i;
  return (ush)((u + 0x7fffu + ((u>>16)&1u)) >> 16);
}

typedef __attribute__((address_space(1))) void gvoid;
typedef __attribute__((address_space(3))) void lvoid;
DEV void gload16(const void* g, void* l){
  __builtin_amdgcn_global_load_lds((gvoid*)g, (lvoid*)l, 16, 0, 0);
}

DEV void st16(ush* dst, const ush* a){
  *(int4*)dst = *(const int4*)a; *(int4*)(dst+8) = *(const int4*)(a+8);
}

struct GA {
  const ush *A0h, *A0l; long lda0;
  const ush *A1h, *A1l; long lda1; int ksplit;
  const ush *Bh, *Bl; long ldb;
  int K, M, N;
  float alpha, beta;
  long sA, sB, sO, sD;
  void *o0,*o1,*o2,*o3,*o4;
  const void *e0,*e1;
  long ldo0, ldo1, ldE;
};

enum { E_F32=0, E_BF16=1, E_BF16T2=2, E_SPLIT=3, E_QW=4, E_PRE=5, E_GH=6, E_OUT=7 };

template<int BM, int BN, int EPI, bool SPLIT, bool TRX>
__global__ __launch_bounds__(256) void gemm_k(GA gq, GA gr, int zsplit)
{
  // ---- shared memory: NBUF staging buffers, tb aliased on top ------------
  constexpr int AH = BM*32;                        // ush per A panel
  constexpr int BH = BN*32;                        // ush per B panel
  constexpr int PANEL = (AH+BH) * (SPLIT ? 2 : 1); // one buffer (ush)
  constexpr int DEPTH = (PANEL <= 4096) ? 2 : 1;   // prefetch depth
  constexpr int NBUF  = DEPTH + 2;
  constexpr int TBN = TRX ? 64*65*2 : 0;           // tb as ush count
  constexpr int SMN = (NBUF*PANEL > TBN) ? NBUF*PANEL : TBN;
  __shared__ ush smem[SMN] __attribute__((aligned(16)));
  uint32* tb = (uint32*)smem;                      // valid only after k-loop

  // loads issued per thread per STAGE (compile-time)
  constexpr int LPS = (BM/64 + BN/64) * (SPLIT ? 2 : 1);

  GA g; int bz;
  if ((int)blockIdx.z < zsplit){ g = gq; bz = blockIdx.z; }
  else                         { g = gr; bz = blockIdx.z - zsplit; }

  // supertile swizzle: groups of 8 block-rows, column-major inside a group
  const int gx = gridDim.x, gy = gridDim.y;
  const int lin = blockIdx.y*gx + blockIdx.x;
  const int per = gx*8;
  const int grp = lin / per;
  const int rem = lin - grp*per;
  int gh = gy - grp*8; if (gh > 8) gh = 8;
  const int by = grp*8 + rem % gh;
  const int bx = rem / gh;
  const int m0 = by * BM;
  const int n0 = bx * BN;
  if (m0 >= g.M || n0 >= g.N) return;

  const int t = threadIdx.x;
  const int lane = t & 63;
  const int wave = t >> 6;
  const int wm = (wave >> 1) * (BM/2);
  const int wn = (wave & 1) * (BN/2);
  constexpr int MT = BM/32;
  constexpr int NT = BN/32;

  const ush* Ah  = g.A0h + (long)bz*g.sA;
  const ush* Alp = SPLIT ? g.A0l + (long)bz*g.sA : nullptr;
  const ush* Bhp = g.Bh  + (long)bz*g.sB;
  const ush* Blp = SPLIT ? g.Bl  + (long)bz*g.sB : nullptr;

  f4v acc[MT][NT];
  #pragma unroll
  for (int i=0;i<MT;i++)
    #pragma unroll
    for (int j=0;j<NT;j++) acc[i][j] = f4v{0.f,0.f,0.f,0.f};

  const int sr  = lane >> 2;
  const int scg = lane & 3;

  // stage one 32-K tile into buffer nb (0..NBUF-1)
  auto STAGE = [&](int k0, int nb){
    ush* dA  = smem + nb*PANEL;
    ush* dB  = dA + AH;
    ush* dAl = dB + BH;
    ush* dBl = dAl + AH;
    #pragma unroll
    for (int p = 0; p < BM/64; ++p) {
      const int lr = wave*16 + sr + p*64;
      const int gc = scg ^ ((lr>>1)&3);
      const int kc = k0 + gc*8;
      long aoff; const ush* gp;
      if (kc < g.ksplit){ aoff = (long)(m0+lr)*g.lda0 + kc;               gp = Ah + aoff; }
      else              { aoff = (long)(m0+lr)*g.lda1 + (kc - g.ksplit);  gp = g.A1h + aoff; }
      gload16(gp, &dA[(wave*16 + p*64)*32]);
      if (SPLIT) gload16(Alp + aoff, &dAl[(wave*16 + p*64)*32]);
    }
    #pragma unroll
    for (int p = 0; p < BN/64; ++p) {
      const int lr = wave*16 + sr + p*64;
      const int gc = scg ^ ((lr>>1)&3);
      const long boff = (long)(n0+lr)*g.ldb + k0 + gc*8;
      gload16(Bhp + boff, &dB[(wave*16 + p*64)*32]);
      if (SPLIT) gload16(Blp + boff, &dBl[(wave*16 + p*64)*32]);
    }
  };

  // ---- K-loop: depth-DEPTH prefetch, counted vmcnt, ONE s_barrier/step ----
  STAGE(0, 0);
  if (DEPTH == 2 && g.K > 32) STAGE(32, 1);
  int cur = 0;
  for (int k0 = 0; k0 < g.K; k0 += 32) {
    const int rem_steps = ((g.K - k0) >> 5) - 1;   // steps after current
    if (DEPTH == 2) {
      if (rem_steps >= 2) {
        const int nb = (cur+2 >= NBUF) ? cur+2-NBUF : cur+2;
        STAGE(k0 + 64, nb);
        asm volatile("s_waitcnt vmcnt(%0)" :: "n"(2*LPS) : "memory");
      } else if (rem_steps == 1) {
        asm volatile("s_waitcnt vmcnt(%0)" :: "n"(LPS) : "memory");
      } else {
        asm volatile("s_waitcnt vmcnt(0)" ::: "memory");
      }
    } else {
      if (rem_steps >= 1) {
        const int nb = (cur+1 >= NBUF) ? cur+1-NBUF : cur+1;
        STAGE(k0 + 32, nb);
        asm volatile("s_waitcnt vmcnt(%0)" :: "n"(LPS) : "memory");
      } else {
        asm volatile("s_waitcnt vmcnt(0)" ::: "memory");
      }
    }
    __builtin_amdgcn_sched_barrier(0);
    __builtin_amdgcn_s_barrier();      // all waves have buf(cur) resident
    __builtin_amdgcn_sched_barrier(0);

    const ush* rA  = smem + cur*PANEL;
    const ush* rB  = rA + AH;
    const ush* rAl = rB + BH;
    const ush* rBl = rAl + AH;

    const int fr = lane & 15;
    const int cc = lane >> 4;
    s8v af[MT], bf_[NT];
    #pragma unroll
    for (int i=0;i<MT;i++){ const int row = wm + i*16 + fr;
      af[i] = *(const s8v*)(&rA[row*32 + ((cc ^ ((row>>1)&3))<<3)]); }
    #pragma unroll
    for (int j=0;j<NT;j++){ const int row = wn + j*16 + fr;
      bf_[j] = *(const s8v*)(&rB[row*32 + ((cc ^ ((row>>1)&3))<<3)]); }
    #pragma unroll
    for (int i=0;i<MT;i++)
      #pragma unroll
      for (int j=0;j<NT;j++)
        acc[i][j] = __builtin_amdgcn_mfma_f32_16x16x32_bf16(af[i], bf_[j], acc[i][j], 0,0,0);
    if (SPLIT) {
      s8v al2[MT], bl2[NT];
      #pragma unroll
      for (int j=0;j<NT;j++){ const int row = wn + j*16 + fr;
        bl2[j] = *(const s8v*)(&rBl[row*32 + ((cc ^ ((row>>1)&3))<<3)]); }
      #pragma unroll
      for (int i=0;i<MT;i++){ const int row = wm + i*16 + fr;
        al2[i] = *(const s8v*)(&rAl[row*32 + ((cc ^ ((row>>1)&3))<<3)]); }
      #pragma unroll
      for (int i=0;i<MT;i++)
        #pragma unroll
        for (int j=0;j<NT;j++)
          acc[i][j] = __builtin_amdgcn_mfma_f32_16x16x32_bf16(af[i], bl2[j], acc[i][j], 0,0,0);
      #pragma unroll
      for (int i=0;i<MT;i++)
        #pragma unroll
        for (int j=0;j<NT;j++)
          acc[i][j] = __builtin_amdgcn_mfma_f32_16x16x32_bf16(al2[i], bf_[j], acc[i][j], 0,0,0);
    }
    cur = (cur+1 >= NBUF) ? 0 : cur+1;
  }

  // before epilogue: TRX writes tb over the staging alias -> need all waves
  // past their final MFMA reads of smem.
  if constexpr (TRX) __syncthreads();

  // ---------------- epilogue: direct writes (+ LDS staging for TRX) --------
  #pragma unroll
  for (int i=0;i<MT;i++)
    #pragma unroll
    for (int j=0;j<NT;j++)
      #pragma unroll
      for (int r=0;r<4;r++) {
        const int lrow = wm + i*16 + ((lane>>4)<<2) + r;
        const int lcol = wn + j*16 + (lane & 15);
        const int grow = m0 + lrow;
        const int gcol = n0 + lcol;
        float v = g.alpha * acc[i][j][r];
        if constexpr (EPI == E_F32) {
          if (g.e0) v += g.beta * ((const float*)g.e0)[(long)bz*g.sD + (long)grow*g.ldo0 + gcol];
          ((float*)g.o0)[(long)bz*g.sO + (long)grow*g.ldo0 + gcol] = v;
        } else if constexpr (EPI == E_BF16) {
          if (g.e0) v += g.beta * b2f(((const ush*)g.e0)[(long)bz*g.sD + (long)grow*g.ldo0 + gcol]);
          ((ush*)g.o0)[(long)bz*g.sO + (long)grow*g.ldo0 + gcol] = f2b(v);
        } else if constexpr (EPI == E_BF16T2) {
          if (g.e0) v += g.beta * b2f(((const ush*)g.e0)[(long)bz*g.sD + (long)grow*g.ldo0 + gcol]);
          ush hv = f2b(v);
          ((ush*)g.o0)[(long)bz*g.sO + (long)grow*g.ldo0 + gcol] = hv;
          tb[lrow*65 + lcol] = hv;
        } else if constexpr (EPI == E_SPLIT) {
          if (g.e0) v += g.beta * ((const float*)g.e0)[(long)bz*g.sD + (long)grow*g.ldo0 + gcol];
          if (g.o0) ((float*)g.o0)[(long)bz*g.sO + (long)grow*g.ldo0 + gcol] = v;
          ush hv = f2b(v);
          ush lv = f2b(v - b2f(hv));
          ((ush*)g.o1)[(long)bz*g.sO + (long)grow*g.ldo0 + gcol] = hv;
          ((ush*)g.o2)[(long)bz*g.sO + (long)grow*g.ldo0 + gcol] = lv;
          if (TRX) tb[lrow*65 + lcol] = (uint32)hv | ((uint32)lv<<16);
        } else if constexpr (EPI == E_QW) {
          ush hv = f2b(v);
          ((ush*)g.o0)[(long)bz*g.sO + (long)grow*g.ldo0 + gcol] = hv;
          tb[lrow*65 + lcol] = hv;
        } else if constexpr (EPI == E_PRE) {
          v += ((const float*)g.e0)[gcol];
          v = v > 0.f ? v : 0.f;
          ((ush*)g.o0)[(long)grow*g.ldo0 + gcol] = f2b(v);
        } else if constexpr (EPI == E_GH) {
          if (gcol < 512) {
            float h = v - b2f(((const ush*)g.e0)[(long)grow*g.ldE + gcol]);
            ush hb = f2b(h);
            ((ush*)g.o0)[(long)grow*512 + gcol] = hb;
            if (g.o2) ((ush*)g.o2)[(long)grow*4096 + gcol] = hb;
          } else {
            float y = b2f(((const ush*)g.e1)[(long)grow*512 + (gcol-512)]) - v;
            ((ush*)g.o1)[(long)grow*4096 + (gcol-512)] = f2b(y);
          }
        } else if constexpr (EPI == E_OUT) {
          float o = 0.5f*(10.1f*((const float*)g.e0)[(long)grow*1024 + gcol] + v)
                  + ((const float*)g.e1)[gcol];
          ((float*)g.o0)[(long)grow*1024 + gcol] = o;
        }
      }

  // ---------------- transposed writes (coalesced via LDS) ------------------
  if constexpr (TRX) {
    __syncthreads();
    const int tr  = t >> 2;     // transposed row = original col
    const int seg = t & 3;
    uint32 vals[16];
    #pragma unroll
    for (int u=0;u<16;u++) vals[u] = tb[(seg*16+u)*65 + tr];
    ush hb[16] __attribute__((aligned(16)));
    ush lb[16] __attribute__((aligned(16)));
    #pragma unroll
    for (int u=0;u<16;u++){ hb[u] = (ush)(vals[u]&0xffffu); lb[u] = (ush)(vals[u]>>16); }
    const long bT = (long)bz*g.sO + (long)(n0+tr)*g.ldo1 + m0 + seg*16;
    if constexpr (EPI == E_BF16T2) {
      st16((ush*)g.o1 + bT, hb);
    } else if constexpr (EPI == E_SPLIT) {
      if (g.o3) { st16((ush*)g.o3 + bT, hb); st16((ush*)g.o4 + bT, lb); }
    } else if constexpr (EPI == E_QW) {
      st16((ush*)g.o1 + bT, hb);
    }
  }
}

// ------------------------------ small kernels ------------------------------

__global__ __launch_bounds__(256) void k_norms(const float* __restrict__ Fq,
    const float* __restrict__ Fr0, const float* __restrict__ Frr, float* s2){
  const int y = blockIdx.y;
  const float* p; long cnt4;
  if (y==0){ p=Fq; cnt4=1048576l; }
  else if (y==1){ p=Fr0; cnt4=65536l; }
  else { p=Frr + (long)(y-2)*524288; cnt4=131072l; }
  float s = 0.f;
  for (long i = (long)blockIdx.x*256 + threadIdx.x; i < cnt4; i += (long)gridDim.x*256){
    float4 v = ((const float4*)p)[i];
    s += v.x*v.x + v.y*v.y + v.z*v.z + v.w*v.w;
  }
  #pragma unroll
  for (int o=32;o>0;o>>=1) s += __shfl_down(s, o, 64);
  __shared__ float red[4];
  if ((threadIdx.x & 63)==0) red[threadIdx.x>>6] = s;
  __syncthreads();
  if (threadIdx.x==0) atomicAdd(&s2[y], red[0]+red[1]+red[2]+red[3]);
}

__global__ void k_scales(const float* s2, const float* fq, const float* fr, float* sc){
  int t = threadIdx.x;
  if (t < 9){
    float v = (t==0)? fq[0] : fr[t-1];
    sc[t] = v / (sqrtf(s2[t]) + 1e-5f);
  }
}

// tiled build of V (3072x1024, z=0) and Wr (7x512x512, z=1..7), hi/lo + transpose
__global__ __launch_bounds__(256) void k_buildT(const float* __restrict__ Fq,
    const float* __restrict__ Frr, const float* sc,
    ush* Vh, ush* Vl, ush* Vth, ush* Vtl,
    ush* Wrh, ush* Wrl, ush* WrTh, ush* WrTl){
  __shared__ uint32 tb[64*65];
  const int z = blockIdx.z;
  const int r = threadIdx.x >> 2;
  const int cs = (threadIdx.x & 3)*16;
  ush hh[16] __attribute__((aligned(16)));
  ush ll[16] __attribute__((aligned(16)));
  if (z==0){
    const long r0 = (long)blockIdx.y*64, c0 = (long)blockIdx.x*64;
    const float s = sc[0];
    const float* src = &Fq[(1024+r0+r)*1024 + c0 + cs];
    #pragma unroll
    for (int u=0;u<16;u++){
      float v = s*src[u];
      ush h = f2b(v); ush l = f2b(v - b2f(h));
      hh[u]=h; ll[u]=l;
      tb[r*65 + cs + u] = (uint32)h | ((uint32)l<<16);
    }
    st16(&Vh[(r0+r)*1024 + c0 + cs], hh);
    st16(&Vl[(r0+r)*1024 + c0 + cs], ll);
    __syncthreads();
    const int tr = threadIdx.x>>2, seg = threadIdx.x&3;
    #pragma unroll
    for (int u=0;u<16;u++){
      uint32 v = tb[(seg*16+u)*65 + tr];
      hh[u]=(ush)(v&0xffffu); ll[u]=(ush)(v>>16);
    }
    st16(&Vth[(c0+tr)*3072 + r0 + seg*16], hh);
    st16(&Vtl[(c0+tr)*3072 + r0 + seg*16], ll);
  } else {
    if (blockIdx.x>=8 || blockIdx.y>=8) return;
    const int k = z-1;
    const long r0 = (long)blockIdx.y*64, c0 = (long)blockIdx.x*64;
    const float s = sc[2+k];
    const float* src = &Frr[(long)k*524288 + (r0+r)*1024 + 512 + c0 + cs];
    #pragma unroll
    for (int u=0;u<16;u++){
      float v = s*src[u];
      ush h = f2b(v); ush l = f2b(v - b2f(h));
      hh[u]=h; ll[u]=l;
      tb[r*65 + cs + u] = (uint32)h | ((uint32)l<<16);
    }
    st16(&Wrh[(long)k*262144 + (r0+r)*512 + c0 + cs], hh);
    st16(&Wrl[(long)k*262144 + (r0+r)*512 + c0 + cs], ll);
    __syncthreads();
    const int tr = threadIdx.x>>2, seg = threadIdx.x&3;
    #pragma unroll
    for (int u=0;u<16;u++){
      uint32 v = tb[(seg*16+u)*65 + tr];
      hh[u]=(ush)(v&0xffffu); ll[u]=(ush)(v>>16);
    }
    st16(&WrTh[(long)k*262144 + (c0+tr)*512 + r0 + seg*16], hh);
    st16(&WrTl[(long)k*262144 + (c0+tr)*512 + r0 + seg*16], ll);
  }
}

// tiled assembly of M = I + A (hi/lo) and M^T: z=0 Q (16x16 tiles), z=1..8 R (8x8)
__global__ __launch_bounds__(256) void k_asmT(const float* __restrict__ Fq,
    const float* __restrict__ Fr0, const float* __restrict__ Frr,
    const float* sc, const float* __restrict__ PP,
    ush* Mh, ush* Ml, ush* MTh, ush* MTl){
  __shared__ uint32 tb[64*65];
  const int z = blockIdx.z;
  const int r = threadIdx.x >> 2;
  const int cs = (threadIdx.x & 3)*16;
  const long ROFF = 1048576l, RS = 262144l;
  long r0 = (long)blockIdx.y*64, c0 = (long)blockIdx.x*64;
  const float* dsrc; const float* msrc; const float* psrc = nullptr;
  float s; long obase; long old_; float sgn;
  if (z==0){
    s = sc[0]; sgn = 1.f;
    dsrc = &Fq[(r0+r)*1024 + c0 + cs];
    msrc = &Fq[(c0+r)*1024 + r0 + cs];
    psrc = &PP[(r0+r)*1024 + c0 + cs];
    obase = 0; old_ = 1024;
  } else {
    if (blockIdx.x>=8 || blockIdx.y>=8) return;
    const int b = z-1;
    if (b==0){
      s = sc[1]; sgn = 1.f;
      dsrc = &Fr0[(r0+r)*512 + c0 + cs];
      msrc = &Fr0[(c0+r)*512 + r0 + cs];
    } else {
      s = sc[1+b]; sgn = -1.f;   // a = s*(W[c][r]-W[r][c]) = s*(mirror-direct)
      const float* W = Frr + (long)(b-1)*524288;
      dsrc = &W[(r0+r)*1024 + c0 + cs];
      msrc = &W[(c0+r)*1024 + r0 + cs];
      psrc = &PP[ROFF + (long)(b-1)*RS + (r0+r)*512 + c0 + cs];
    }
    obase = ROFF + (long)b*RS; old_ = 512;
  }
  // stage mirror tile (float bits)
  #pragma unroll
  for (int u=0;u<16;u++) tb[r*65 + cs + u] = __float_as_uint(msrc[u]);
  __syncthreads();
  ush hh[16] __attribute__((aligned(16)));
  ush ll[16] __attribute__((aligned(16)));
  #pragma unroll
  for (int u=0;u<16;u++){
    const int c = cs + u;
    float mir = __uint_as_float(tb[c*65 + r]);
    float a = sgn * s * (dsrc[u] - mir);
    if (psrc) a += psrc[u];
    float m = ((r0 + r == c0 + c) ? 1.f : 0.f) + a;
    ush h = f2b(m); ush l = f2b(m - b2f(h));
    hh[u]=h; ll[u]=l;
  }
  st16(&Mh[obase + (r0+r)*old_ + c0 + cs], hh);
  st16(&Ml[obase + (r0+r)*old_ + c0 + cs], ll);
  __syncthreads();
  #pragma unroll
  for (int u=0;u<16;u++) tb[r*65 + cs + u] = (uint32)hh[u] | ((uint32)ll[u]<<16);
  __syncthreads();
  const int tr = threadIdx.x>>2, seg = threadIdx.x&3;
  #pragma unroll
  for (int u=0;u<16;u++){
    uint32 v = tb[(seg*16+u)*65 + tr];
    hh[u]=(ush)(v&0xffffu); ll[u]=(ush)(v>>16);
  }
  st16(&MTh[obase + (c0+tr)*old_ + r0 + seg*16], hh);
  st16(&MTl[obase + (c0+tr)*old_ + r0 + seg*16], ll);
}

__global__ __launch_bounds__(256) void k_rowabs(const float* __restrict__ T2, float* bmax){
  const int y = blockIdx.y;
  const float* row; int n;
  if (y==0){ row = T2 + (long)blockIdx.x*1024; n = 1024; }
  else { if (blockIdx.x >= 512) return;
         row = T2 + 1048576l + (long)(y-1)*262144 + (long)blockIdx.x*512; n = 512; }
  float s=0.f;
  for (int i=threadIdx.x;i<n;i+=256) s += fabsf(row[i]);
  #pragma unroll
  for (int o=32;o>0;o>>=1) s += __shfl_down(s,o,64);
  __shared__ float red[4];
  if ((threadIdx.x&63)==0) red[threadIdx.x>>6]=s;
  __syncthreads();
  if (threadIdx.x==0){
    float tot = red[0]+red[1]+red[2]+red[3];
    atomicMax((unsigned int*)&bmax[y], __float_as_uint(tot));
  }
}

__global__ void k_makec(const float* bmax, float* cvl){
  int t=threadIdx.x;
  if (t<9){
    float bnd = sqrtf(fmaxf(bmax[t], 1.f));   // >= sigma_max(M)^2
    cvl[t] = 1.9f/(1.f + bnd);
  }
}

__global__ __launch_bounds__(256) void k_initX(const ush* __restrict__ Mh,
    const ush* __restrict__ MTh, const float* cvl, ush* Xh, ush* XTh){
  long i = (long)blockIdx.x*256 + threadIdx.x;
  int b = (i < 1048576l) ? 0 : 1 + (int)((i - 1048576l) >> 18);
  float c = cvl[b];
  Xh[i]  = f2b(c * b2f(MTh[i]));
  XTh[i] = f2b(c * b2f(Mh[i]));
}

__global__ __launch_bounds__(256) void k_promote(const ush* __restrict__ Xh,
    float* Xf, ush* Xl, ush* XTl){
  long i = (long)blockIdx.x*256 + threadIdx.x;
  Xf[i] = b2f(Xh[i]);
  Xl[i] = 0; XTl[i] = 0;
}

// tops: 2X - I, tiled, value + transposed copy.  z=0 Q (16x16), z=1..8 R (8x8)
__global__ __launch_bounds__(256) void k_topT(const ush* __restrict__ Xh, const ush* __restrict__ Xl,
    ush* Qb, ush* QTb, ush* RK, ush* RKT){
  __shared__ uint32 tb[64*65];
  const int z = blockIdx.z;
  const int r = threadIdx.x >> 2;
  const int cs = (threadIdx.x & 3)*16;
  const long ROFF = 1048576l, RS = 262144l;
  long r0 = (long)blockIdx.y*64, c0 = (long)blockIdx.x*64;
  ush hh[16] __attribute__((aligned(16)));
  if (z==0){
    const long base = (r0+r)*1024 + c0 + cs;
    #pragma unroll
    for (int u=0;u<16;u++){
      float v = 2.f*(b2f(Xh[base+u]) + b2f(Xl[base+u])) - ((r0+r == c0+cs+u)?1.f:0.f);
      hh[u] = f2b(v);
      tb[r*65 + cs + u] = hh[u];
    }
    st16(&Qb[(r0+r)*1024 + c0 + cs], hh);
    __syncthreads();
    const int tr = threadIdx.x>>2, seg = threadIdx.x&3;
    #pragma unroll
    for (int u=0;u<16;u++) hh[u] = (ush)tb[(seg*16+u)*65 + tr];
    st16(&QTb[(c0+tr)*4096 + r0 + seg*16], hh);
  } else {
    if (blockIdx.x>=8 || blockIdx.y>=8) return;
    const int b = z-1;
    const long base = ROFF + (long)b*RS + (r0+r)*512 + c0 + cs;
    #pragma unroll
    for (int u=0;u<16;u++){
      float v = 2.f*(b2f(Xh[base+u]) + b2f(Xl[base+u])) - ((r0+r == c0+cs+u)?1.f:0.f);
      hh[u] = f2b(v);
      tb[r*65 + cs + u] = hh[u];
    }
    st16(&RKT[(long)b*524288 + (r0+r)*512 + c0 + cs], hh);
    __syncthreads();
    const int tr = threadIdx.x>>2, seg = threadIdx.x&3;
    #pragma unroll
    for (int u=0;u<16;u++) hh[u] = (ush)tb[(seg*16+u)*65 + tr];
    st16(&RK[(long)b*524288 + (c0+tr)*1024 + r0 + seg*16], hh);
  }
}

__global__ __launch_bounds__(256) void k_f2bf(const float* __restrict__ in, ush* __restrict__ o){
  long i = ((long)blockIdx.x*256 + threadIdx.x)*8;
  float4 a = *(const float4*)(in+i);
  float4 b = *(const float4*)(in+i+4);
  ush u[8] __attribute__((aligned(16)));
  u[0]=f2b(a.x);u[1]=f2b(a.y);u[2]=f2b(a.z);u[3]=f2b(a.w);
  u[4]=f2b(b.x);u[5]=f2b(b.y);u[6]=f2b(b.z);u[7]=f2b(b.w);
  *(int4*)(o+i) = *(const int4*)u;
}

// ------------------------------ host driver -------------------------------

static GA mk(const ush* Ah, const ush* Al, long lda,
             const ush* Bh, const ush* Bl, long ldb,
             int K, int M, int N, float alpha){
  GA g{}; g.ksplit=1<<30; g.A0h=Ah; g.A0l=Al; g.lda0=lda;
  g.Bh=Bh; g.Bl=Bl; g.ldb=ldb; g.K=K; g.M=M; g.N=N; g.alpha=alpha; g.beta=0.f;
  return g;
}

extern "C" void kernel_launch(void* const* d_in, const int* in_sizes, int n_in,
                              void* d_out, int out_size, void* d_ws, size_t ws_size,
                              hipStream_t stream)
{
  (void)in_sizes; (void)n_in; (void)out_size; (void)ws_size;
  const float* x   = (const float*)d_in[0];
  const float* Fq  = (const float*)d_in[1];
  const float* fqp = (const float*)d_in[2];
  const float* by  = (const float*)d_in[3];
  const float* Fr0 = (const float*)d_in[4];
  const float* Frr = (const float*)d_in[5];
  const float* frp = (const float*)d_in[6];
  const float* bp  = (const float*)d_in[7];
  float* out = (float*)d_out;

  const float SQG = sqrtf(10.0f - 0.1f);
  const float SQ2 = sqrtf(2.0f);
  const long UN = 3145728l;
  const long ROFF = 1048576l, RS = 262144l;

  char* base = (char*)d_ws;
  size_t off = 0;
  auto alloc = [&](size_t bytes)->char*{
    char* p = base + off; off = (off + bytes + 255) & ~(size_t)255; return p;
  };

  // ---- persistent ----
  ush* Qb  = (ush*)alloc(4194304l*2);
  ush* QTb = (ush*)alloc(4194304l*2);
  ush* RK  = (ush*)alloc(4194304l*2);
  ush* RKT = (ush*)alloc(4194304l*2);
  ush* xbf = (ush*)alloc(8388608l*2);
  float* scal = (float*)alloc(256*4);
  float* s2   = scal;
  float* bmax = scal + 16;
  float* cvl  = scal + 32;
  float* sc   = scal + 48;

  const size_t scratch0 = off;
  ush* Vh   = (ush*)alloc(UN*2);
  ush* Vl   = (ush*)alloc(UN*2);
  ush* Vth  = (ush*)alloc(UN*2);
  ush* Vtl  = (ush*)alloc(UN*2);
  ush* Wrh  = (ush*)alloc(1835008l*2);
  ush* Wrl  = (ush*)alloc(1835008l*2);
  ush* WrTh = (ush*)alloc(1835008l*2);
  ush* WrTl = (ush*)alloc(1835008l*2);
  float* PPf = (float*)alloc(UN*4);
  ush* Mh  = (ush*)alloc(UN*2);
  ush* Ml  = (ush*)alloc(UN*2);
  ush* MTh = (ush*)alloc(UN*2);
  ush* MTl = (ush*)alloc(UN*2);
  ush* Sh  = (ush*)alloc(UN*2);
  ush* XhA = (ush*)alloc(UN*2);
  ush* XhB = (ush*)alloc(UN*2);
  ush* XlA = (ush*)alloc(UN*2);
  ush* XlB = (ush*)alloc(UN*2);
  ush* XThA = (ush*)alloc(UN*2);
  ush* XThB = (ush*)alloc(UN*2);
  ush* XTlA = (ush*)alloc(UN*2);
  ush* XTlB = (ush*)alloc(UN*2);
  float* XfA = (float*)alloc(UN*4);
  float* XfB = (float*)alloc(UN*4);
  ush* Yh  = (ush*)alloc(UN*2);
  ush* Yl  = (ush*)alloc(UN*2);

  ush* Xh[2]  = {XhA, XhB};
  ush* Xl[2]  = {XlA, XlB};
  ush* XTh[2] = {XThA, XThB};
  ush* XTl[2] = {XTlA, XTlB};
  float* Xf[2] = {XfA, XfB};

  dim3 B256(256);
  GA ga{}, gr{};

  // ---- phase 0: norms & scales ----
  (void)hipMemsetAsync(scal, 0, 1024, stream);
  k_norms<<<dim3(256,9),B256,0,stream>>>(Fq, Fr0, Frr, s2);
  k_scales<<<1,16,0,stream>>>(s2, fqp, frp, sc);

  // ---- phase 1: build V / Wr (tiled, coalesced) ----
  k_buildT<<<dim3(16,48,8),B256,0,stream>>>(Fq, Frr, sc, Vh,Vl,Vth,Vtl, Wrh,Wrl,WrTh,WrTl);

  // PQ = V^T V ; PR_k = Wr Wr^T (split) -> PPf
  ga = mk(Vth,Vtl,3072, Vth,Vtl,3072, 3072,1024,1024, 1.f); ga.o0=PPf; ga.ldo0=1024;
  gr = mk(Wrh,Wrl,512, Wrh,Wrl,512, 512,512,512, 1.f);
  gr.sA=RS; gr.sB=RS; gr.o0=PPf+ROFF; gr.sO=RS; gr.ldo0=512;
  gemm_k<64,64,E_F32,true,false><<<dim3(16,16,8),B256,0,stream>>>(ga,gr,1);

  // ---- phase 2: assemble M, M^T (tiled) ----
  k_asmT<<<dim3(16,16,9),B256,0,stream>>>(Fq, Fr0, Frr, sc, PPf, Mh,Ml,MTh,MTl);

  // ---- phase 3: bound: S = M*M^T (bf16), S^2 (f32), rowabs, c, X0 ----
  ga = mk(Mh,nullptr,1024, Mh,nullptr,1024, 1024,1024,1024, 1.f); ga.o0=Sh; ga.ldo0=1024;
  gr = mk(Mh+ROFF,nullptr,512, Mh+ROFF,nullptr,512, 512,512,512, 1.f);
  gr.sA=RS; gr.sB=RS; gr.o0=Sh+ROFF; gr.sO=RS; gr.ldo0=512;
  gemm_k<64,64,E_BF16,false,false><<<dim3(16,16,9),B256,0,stream>>>(ga,gr,1);

  ga = mk(Sh,nullptr,1024, Sh,nullptr,1024, 1024,1024,1024, 1.f); ga.o0=PPf; ga.ldo0=1024;
  gr = mk(Sh+ROFF,nullptr,512, Sh+ROFF,nullptr,512, 512,512,512, 1.f);
  gr.sA=RS; gr.sB=RS; gr.o0=PPf+ROFF; gr.sO=RS; gr.ldo0=512;
  gemm_k<64,64,E_F32,false,false><<<dim3(16,16,9),B256,0,stream>>>(ga,gr,1);
  k_rowabs<<<dim3(1024,9),B256,0,stream>>>(PPf, bmax);
  k_makec<<<1,16,0,stream>>>(bmax, cvl);
  k_initX<<<12288,B256,0,stream>>>(Mh, MTh, cvl, Xh[0], XTh[0]);

  // ---- phase 4: coupled NS bf16: Y=(MX)^T ; X' = 2X - X*Y^T  (9 iters) ----
  int cur = 0;
  for (int it=0; it<9; ++it){
    int nxt = cur^1;
    ga = mk(XTh[cur],nullptr,1024, Mh,nullptr,1024, 1024,1024,1024, 1.f); ga.o0=Yh; ga.ldo0=1024;
    gr = mk(XTh[cur]+ROFF,nullptr,512, Mh+ROFF,nullptr,512, 512,512,512, 1.f);
    gr.sA=RS; gr.sB=RS; gr.o0=Yh+ROFF; gr.sO=RS; gr.ldo0=512;
    gemm_k<64,64,E_BF16,false,false><<<dim3(16,16,9),B256,0,stream>>>(ga,gr,1);

    ga = mk(Xh[cur],nullptr,1024, Yh,nullptr,1024, 1024,1024,1024, -1.f);
    ga.beta=2.f; ga.e0=Xh[cur];
    ga.o0=Xh[nxt]; ga.o1=XTh[nxt]; ga.ldo0=1024; ga.ldo1=1024;
    gr = mk(Xh[cur]+ROFF,nullptr,512, Yh+ROFF,nullptr,512, 512,512,512, -1.f);
    gr.beta=2.f; gr.e0=Xh[cur]+ROFF; gr.sD=RS;
    gr.sA=RS; gr.sB=RS; gr.sO=RS;
    gr.o0=Xh[nxt]+ROFF; gr.o1=XTh[nxt]+ROFF; gr.ldo0=512; gr.ldo1=512;
    gemm_k<64,64,E_BF16T2,false,true><<<dim3(16,16,9),B256,0,stream>>>(ga,gr,1);
    cur = nxt;
  }

  // ---- phase 5: promote + 2 split-precision NS iters ----
  k_promote<<<12288,B256,0,stream>>>(Xh[cur], Xf[cur], Xl[cur], XTl[cur]);
  for (int it=0; it<2; ++it){
    int nxt = cur^1;
    ga = mk(XTh[cur],XTl[cur],1024, Mh,Ml,1024, 1024,1024,1024, 1.f);
    ga.o1=Yh; ga.o2=Yl; ga.ldo0=1024;
    gr = mk(XTh[cur]+ROFF,XTl[cur]+ROFF,512, Mh+ROFF,Ml+ROFF,512, 512,512,512, 1.f);
    gr.sA=RS; gr.sB=RS; gr.o1=Yh+ROFF; gr.o2=Yl+ROFF; gr.sO=RS; gr.ldo0=512;
    gemm_k<64,64,E_SPLIT,true,false><<<dim3(16,16,9),B256,0,stream>>>(ga,gr,1);

    ga = mk(Xh[cur],Xl[cur],1024, Yh,Yl,1024, 1024,1024,1024, -1.f);
    ga.beta=2.f; ga.e0=Xf[cur];
    ga.o0=Xf[nxt]; ga.o1=Xh[nxt]; ga.o2=Xl[nxt]; ga.o3=XTh[nxt]; ga.o4=XTl[nxt];
    ga.ldo0=1024; ga.ldo1=1024;
    gr = mk(Xh[cur]+ROFF,Xl[cur]+ROFF,512, Yh+ROFF,Yl+ROFF,512, 512,512,512, -1.f);
    gr.beta=2.f; gr.e0=Xf[cur]+ROFF; gr.sD=RS;
    gr.sA=RS; gr.sB=RS; gr.sO=RS;
    gr.o0=Xf[nxt]+ROFF; gr.o1=Xh[nxt]+ROFF; gr.o2=Xl[nxt]+ROFF;
    gr.o3=XTh[nxt]+ROFF; gr.o4=XTl[nxt]+ROFF;
    gr.ldo0=512; gr.ldo1=512;
    gemm_k<64,64,E_SPLIT,true,true><<<dim3(16,16,9),B256,0,stream>>>(ga,gr,1);
    cur = nxt;
  }

  // ---- phase 6: tops = 2X - I (tiled) ; bottoms = -2*V*X (QW + LDS transpose) ----
  k_topT<<<dim3(16,16,9),B256,0,stream>>>(Xh[cur], Xl[cur], Qb, QTb, RK, RKT);

  ga = mk(Vh,Vl,1024, XTh[cur],XTl[cur],1024, 1024,3072,1024, -2.f);
  ga.o0=Qb + 1048576l; ga.ldo0=1024; ga.o1=QTb + 1024; ga.ldo1=4096;
  gr = mk(WrTh,WrTl,512, XTh[cur]+ROFF+RS, XTl[cur]+ROFF+RS, 512, 512,512,512, -2.f);
  gr.sA=RS; gr.sB=RS; gr.sO=524288;
  gr.o0=RKT + 524288 + 262144; gr.ldo0=512;
  gr.o1=RK + 524288 + 512; gr.ldo1=1024;
  gemm_k<64,64,E_QW,true,true><<<dim3(16,48,8),B256,0,stream>>>(ga,gr,1);

  // ---- main-path overlay buffers ----
  off = scratch0;
  ush* xh  = (ush*)alloc(33554432l*2);
  ush* yh  = (ush*)alloc(33554432l*2);
  ush* pre = (ush*)alloc(4194304l*2);
  ush* h0  = (ush*)alloc(4194304l*2);
  ush* h1  = (ush*)alloc(4194304l*2);

  // ---- phase 7: main chain ----
  k_f2bf<<<4096,B256,0,stream>>>(x, xbf);
  ga = mk(xbf,nullptr,1024, Qb,nullptr,1024, 1024,8192,4096, SQG);
  ga.o0=xh; ga.ldo0=4096;
  gemm_k<128,128,E_BF16,false,false><<<dim3(32,64,1),B256,0,stream>>>(ga,ga,1);

  for (int k=0;k<8;++k){
    ush* hprev = (k==0)? nullptr : (((k-1)&1) ? h1 : h0);
    ush* hnew  = (k&1) ? h1 : h0;
    GA gp_ = mk(xh + (long)k*512, nullptr, 4096,
                (k==0)? RKT : RK + (long)k*524288, nullptr, (k==0)?512:1024,
                (k==0)?512:1024, 8192, 512, SQ2);
    gp_.ksplit = 512; gp_.A1h = hprev; gp_.lda1 = 512;
    gp_.e0 = bp + (long)k*512; gp_.o0 = pre; gp_.ldo0 = 512;
    gemm_k<128,64,E_PRE,false,false><<<dim3(8,64,1),B256,0,stream>>>(gp_,gp_,1);

    GA gg = mk(pre, nullptr, 512,
               (k==0)? RK : RKT + (long)k*524288, nullptr, (k==0)?1024:512,
               512, 8192, (k==0)?512:1024, SQ2);
    gg.e0 = xh + (long)k*512; gg.ldE = 4096;
    gg.e1 = hprev;
    gg.o0 = hnew;
    gg.o1 = (k>=1)? (void*)(yh + (long)(k-1)*512) : nullptr;
    gg.o2 = (k==7)? (void*)(yh + 3584) : nullptr;
    if (k==0) gemm_k<128,64,E_GH,false,false><<<dim3(8,64,1),B256,0,stream>>>(gg,gg,1);
    else      gemm_k<128,128,E_GH,false,false><<<dim3(8,64,1),B256,0,stream>>>(gg,gg,1);
  }

  // out = 0.5*(10.1*x + sqrt_gam*(yh@Q)) + by
  ga = mk(yh,nullptr,4096, QTb,nullptr,4096, 4096,8192,1024, SQG);
  ga.e0=x; ga.e1=by; ga.o0=out; ga.ldo0=1024;
  gemm_k<128,128,E_OUT,false,false><<<dim3(8,64,1),B256,0,stream>>>(ga,ga,1);
}